// Round 1
// baseline (512.548 us; speedup 1.0000x reference)
//
#include <hip/hip_runtime.h>

#define NUSERS 100000
#define NITEMS 50000
#define EMB 64

// ---- degree histogram: deg[row[e]] += 1 (self loop added as +1 later) ----
__global__ void deg_kernel(const int* __restrict__ row, unsigned* __restrict__ deg, int E) {
    int i = blockIdx.x * blockDim.x + threadIdx.x;
    if (i < E) atomicAdd(&deg[row[i]], 1u);
}

// ---- inv[i] = rsqrt(deg[i] + 1)  (the +1 is the self loop) ----
__global__ void inv_kernel(const unsigned* __restrict__ deg, float* __restrict__ inv, int n) {
    int i = blockIdx.x * blockDim.x + threadIdx.x;
    if (i < n) inv[i] = rsqrtf((float)(deg[i] + 1u));
}

// ---- scatter: agg[row[e], :] += W[col[e], :] * inv[row]*inv[col] ----
// one 64-lane wave per edge; lane = emb element. 256 threads = 4 edges/block.
__global__ void scatter_kernel(const int* __restrict__ row, const int* __restrict__ col,
                               const float* __restrict__ W, const float* __restrict__ inv,
                               float* __restrict__ agg, int E) {
    int e = blockIdx.x * 4 + (threadIdx.x >> 6);
    int lane = threadIdx.x & 63;
    if (e < E) {
        int r = row[e];
        int c = col[e];
        float norm = inv[r] * inv[c];
        atomicAdd(&agg[(size_t)r * EMB + lane], W[(size_t)c * EMB + lane] * norm);
    }
}

// ---- epilogue: out = relu(agg + W[i]*inv[i]^2 + b), in place on agg ----
__global__ void epilogue_kernel(const float* __restrict__ W, const float* __restrict__ b,
                                const float* __restrict__ inv, float* __restrict__ agg, int n) {
    int i = blockIdx.x * 4 + (threadIdx.x >> 6);
    int lane = threadIdx.x & 63;
    if (i < n) {
        float is = inv[i];
        float v = agg[(size_t)i * EMB + lane] + W[(size_t)i * EMB + lane] * (is * is) + b[lane];
        agg[(size_t)i * EMB + lane] = fmaxf(v, 0.0f);
    }
}

extern "C" void kernel_launch(void* const* d_in, const int* in_sizes, int n_in,
                              void* d_out, int out_size, void* d_ws, size_t ws_size,
                              hipStream_t stream) {
    const int*   ue = (const int*)d_in[0];   // user_edge_index (2, E_U)
    const int*   ie = (const int*)d_in[1];   // item_edge_index (2, E_I)
    const float* Wu = (const float*)d_in[2]; // (NUSERS, 64)
    const float* bu = (const float*)d_in[3]; // (64,)
    const float* Wi = (const float*)d_in[4]; // (NITEMS, 64)
    const float* bi = (const float*)d_in[5]; // (64,)

    const int E_U = in_sizes[0] / 2;
    const int E_I = in_sizes[1] / 2;

    float* out   = (float*)d_out;
    float* out_u = out;                       // [NUSERS, 64]
    float* out_i = out + (size_t)NUSERS * EMB; // [NITEMS, 64]

    // workspace layout: deg_u | deg_i | inv_u | inv_i
    unsigned* deg_u = (unsigned*)d_ws;
    unsigned* deg_i = deg_u + NUSERS;
    float*    inv_u = (float*)(deg_i + NITEMS);
    float*    inv_i = inv_u + NUSERS;

    // zero accumulators + degree counters (stream-ordered, graph-capture safe)
    hipMemsetAsync(d_out, 0, (size_t)out_size * sizeof(float), stream);
    hipMemsetAsync(d_ws, 0, (size_t)(NUSERS + NITEMS) * sizeof(unsigned), stream);

    deg_kernel<<<(E_U + 255) / 256, 256, 0, stream>>>(ue, deg_u, E_U);
    deg_kernel<<<(E_I + 255) / 256, 256, 0, stream>>>(ie, deg_i, E_I);

    inv_kernel<<<(NUSERS + 255) / 256, 256, 0, stream>>>(deg_u, inv_u, NUSERS);
    inv_kernel<<<(NITEMS + 255) / 256, 256, 0, stream>>>(deg_i, inv_i, NITEMS);

    scatter_kernel<<<(E_U + 3) / 4, 256, 0, stream>>>(ue, ue + E_U, Wu, inv_u, out_u, E_U);
    scatter_kernel<<<(E_I + 3) / 4, 256, 0, stream>>>(ie, ie + E_I, Wi, inv_i, out_i, E_I);

    epilogue_kernel<<<(NUSERS + 3) / 4, 256, 0, stream>>>(Wu, bu, inv_u, out_u, NUSERS);
    epilogue_kernel<<<(NITEMS + 3) / 4, 256, 0, stream>>>(Wi, bi, inv_i, out_i, NITEMS);
}

// Round 2
// 370.974 us; speedup vs baseline: 1.3816x; 1.3816x over previous
//
#include <hip/hip_runtime.h>

#define NUSERS 100000
#define NITEMS 50000
#define EMB 64

// ---- degree histogram: deg[row[e]] += 1 ----
__global__ void deg_kernel(const int* __restrict__ row, unsigned* __restrict__ deg, int E) {
    int i = blockIdx.x * blockDim.x + threadIdx.x;
    if (i < E) atomicAdd(&deg[row[i]], 1u);
}

// ---- inv[i] = rsqrt(deg[i] + 1)  (+1 = self loop) ----
__global__ void inv_kernel(const unsigned* __restrict__ deg, float* __restrict__ inv, int n) {
    int i = blockIdx.x * blockDim.x + threadIdx.x;
    if (i < n) inv[i] = rsqrtf((float)(deg[i] + 1u));
}

// ---- scan phase 1: per-1024-chunk block sums ----
__global__ void scan1_kernel(const unsigned* __restrict__ deg, unsigned* __restrict__ part, int n) {
    __shared__ unsigned sh[256];
    int base = blockIdx.x * 1024;
    unsigned s = 0;
    for (int i = threadIdx.x; i < 1024; i += 256) {
        int idx = base + i;
        if (idx < n) s += deg[idx];
    }
    sh[threadIdx.x] = s;
    __syncthreads();
    for (int off = 128; off > 0; off >>= 1) {
        if (threadIdx.x < off) sh[threadIdx.x] += sh[threadIdx.x + off];
        __syncthreads();
    }
    if (threadIdx.x == 0) part[blockIdx.x] = sh[0];
}

// ---- scan phase 2: tiny sequential exclusive scan of block sums (nb <= 128) ----
__global__ void scan2_kernel(unsigned* part, int nb, unsigned* offs_last) {
    if (threadIdx.x == 0 && blockIdx.x == 0) {
        unsigned run = 0;
        for (int i = 0; i < nb; i++) { unsigned v = part[i]; part[i] = run; run += v; }
        *offs_last = run;   // offs[n] = E
    }
}

// ---- scan phase 3: per-chunk exclusive scan -> offs, and init cursor copy ----
__global__ void scan3_kernel(const unsigned* __restrict__ deg, const unsigned* __restrict__ part,
                             unsigned* __restrict__ offs, unsigned* __restrict__ cur, int n) {
    __shared__ unsigned sh[256];
    int t = threadIdx.x;
    int base = blockIdx.x * 1024 + t * 4;
    unsigned v[4];
    unsigned s = 0;
    for (int i = 0; i < 4; i++) {
        int idx = base + i;
        v[i] = (idx < n) ? deg[idx] : 0u;
        s += v[i];
    }
    sh[t] = s;
    __syncthreads();
    // Hillis-Steele inclusive scan over 256 thread sums
    for (int off = 1; off < 256; off <<= 1) {
        unsigned add = (t >= off) ? sh[t - off] : 0u;
        __syncthreads();
        sh[t] += add;
        __syncthreads();
    }
    unsigned running = part[blockIdx.x] + sh[t] - s;  // exclusive prefix for this thread
    for (int i = 0; i < 4; i++) {
        int idx = base + i;
        if (idx < n) { offs[idx] = running; cur[idx] = running; running += v[i]; }
    }
}

// ---- bucket fill: cols_sorted[cursor[row[e]]++] = col[e] ----
__global__ void fill_kernel(const int* __restrict__ row, const int* __restrict__ col,
                            unsigned* __restrict__ cur, int* __restrict__ cols, int E) {
    int e = blockIdx.x * blockDim.x + threadIdx.x;
    if (e < E) {
        unsigned p = atomicAdd(&cur[row[e]], 1u);
        cols[p] = col[e];
    }
}

// ---- gather: one 64-lane wave per output row, fused self-loop + bias + relu ----
__global__ void gather_kernel(const unsigned* __restrict__ offs, const int* __restrict__ cols,
                              const float* __restrict__ W, const float* __restrict__ inv,
                              const float* __restrict__ b, float* __restrict__ out, int n) {
    int r = blockIdx.x * 4 + (threadIdx.x >> 6);
    int lane = threadIdx.x & 63;
    if (r >= n) return;
    unsigned beg = offs[r], end = offs[r + 1];
    float inv_r = inv[r];
    float acc = W[(size_t)r * EMB + lane] * (inv_r * inv_r);   // self loop
    for (unsigned basek = beg; basek < end; basek += 64) {
        int m = (int)min(64u, end - basek);
        int c = 0; float ic = 0.0f;
        if (lane < m) { c = cols[basek + lane]; ic = inv[c]; }  // lane-parallel prefetch
        for (int k = 0; k < m; k++) {
            int   ck  = __shfl(c, k);
            float ick = __shfl(ic, k);
            acc += W[(size_t)ck * EMB + lane] * (inv_r * ick);
        }
    }
    out[(size_t)r * EMB + lane] = fmaxf(acc + b[lane], 0.0f);
}

extern "C" void kernel_launch(void* const* d_in, const int* in_sizes, int n_in,
                              void* d_out, int out_size, void* d_ws, size_t ws_size,
                              hipStream_t stream) {
    const int*   ue = (const int*)d_in[0];   // user_edge_index (2, E_U)
    const int*   ie = (const int*)d_in[1];   // item_edge_index (2, E_I)
    const float* Wu = (const float*)d_in[2];
    const float* bu = (const float*)d_in[3];
    const float* Wi = (const float*)d_in[4];
    const float* bi = (const float*)d_in[5];

    const int E_U = in_sizes[0] / 2;
    const int E_I = in_sizes[1] / 2;

    float* out_u = (float*)d_out;
    float* out_i = out_u + (size_t)NUSERS * EMB;

    // workspace layout (all 4-byte words)
    unsigned* w      = (unsigned*)d_ws;
    unsigned* deg_u  = w;                 w += NUSERS;
    unsigned* deg_i  = w;                 w += NITEMS;
    unsigned* offs_u = w;                 w += NUSERS + 1;
    unsigned* offs_i = w;                 w += NITEMS + 1;
    unsigned* cur_u  = w;                 w += NUSERS;
    unsigned* cur_i  = w;                 w += NITEMS;
    float*    inv_u  = (float*)w;         w += NUSERS;
    float*    inv_i  = (float*)w;         w += NITEMS;
    unsigned* part   = w;                 w += 128;
    int*      cols_u = (int*)w;           w += E_U;
    int*      cols_i = (int*)w;

    const int nb_u = (NUSERS + 1023) / 1024;  // 98
    const int nb_i = (NITEMS + 1023) / 1024;  // 49

    // zero degree counters (everything else is fully overwritten each call)
    hipMemsetAsync(deg_u, 0, (size_t)(NUSERS + NITEMS) * sizeof(unsigned), stream);

    // ---- user graph ----
    deg_kernel<<<(E_U + 255) / 256, 256, 0, stream>>>(ue, deg_u, E_U);
    inv_kernel<<<(NUSERS + 255) / 256, 256, 0, stream>>>(deg_u, inv_u, NUSERS);
    scan1_kernel<<<nb_u, 256, 0, stream>>>(deg_u, part, NUSERS);
    scan2_kernel<<<1, 64, 0, stream>>>(part, nb_u, &offs_u[NUSERS]);
    scan3_kernel<<<nb_u, 256, 0, stream>>>(deg_u, part, offs_u, cur_u, NUSERS);
    fill_kernel<<<(E_U + 255) / 256, 256, 0, stream>>>(ue, ue + E_U, cur_u, cols_u, E_U);
    gather_kernel<<<(NUSERS + 3) / 4, 256, 0, stream>>>(offs_u, cols_u, Wu, inv_u, bu, out_u, NUSERS);

    // ---- item graph ----
    deg_kernel<<<(E_I + 255) / 256, 256, 0, stream>>>(ie, deg_i, E_I);
    inv_kernel<<<(NITEMS + 255) / 256, 256, 0, stream>>>(deg_i, inv_i, NITEMS);
    scan1_kernel<<<nb_i, 256, 0, stream>>>(deg_i, part, NITEMS);
    scan2_kernel<<<1, 64, 0, stream>>>(part, nb_i, &offs_i[NITEMS]);
    scan3_kernel<<<nb_i, 256, 0, stream>>>(deg_i, part, offs_i, cur_i, NITEMS);
    fill_kernel<<<(E_I + 255) / 256, 256, 0, stream>>>(ie, ie + E_I, cur_i, cols_i, E_I);
    gather_kernel<<<(NITEMS + 3) / 4, 256, 0, stream>>>(offs_i, cols_i, Wi, inv_i, bi, out_i, NITEMS);
}

// Round 3
// 240.864 us; speedup vs baseline: 2.1280x; 1.5402x over previous
//
#include <hip/hip_runtime.h>

#define NUSERS 100000
#define NITEMS 50000
#define EMB 64
#define BROWS 1024      // rows per bucket (== scan1 chunk)
#define CHUNK 4096      // edges per block in bucket passes
#define MAXB 128        // max buckets (user: 98, item: 49)

// packed pair: (local_row << 20) | col   (local_row < 1024, col < 2^17)

// ---- A1: coarse bucket histogram (LDS hist -> few global atomics) ----
__global__ void hist_kernel(const int* __restrict__ row, unsigned* __restrict__ bcnt,
                            int E, int nb) {
    __shared__ unsigned h[MAXB];
    for (int i = threadIdx.x; i < nb; i += blockDim.x) h[i] = 0;
    __syncthreads();
    int lo = blockIdx.x * CHUNK, hi = min(lo + CHUNK, E);
    for (int i = lo + threadIdx.x; i < hi; i += blockDim.x)
        atomicAdd(&h[row[i] >> 10], 1u);
    __syncthreads();
    for (int i = threadIdx.x; i < nb; i += blockDim.x)
        if (h[i]) atomicAdd(&bcnt[i], h[i]);
}

// ---- A2: exclusive scan of bucket counts -> boff[nb+1], init cursors ----
__global__ void bscan_kernel(const unsigned* __restrict__ bcnt, unsigned* __restrict__ boff,
                             unsigned* __restrict__ cursor, int nb) {
    __shared__ unsigned v[MAXB + 1];
    int t = threadIdx.x;
    if (t < nb) v[t] = bcnt[t];
    __syncthreads();
    if (t == 0) {
        unsigned run = 0;
        for (int i = 0; i < nb; i++) { unsigned x = v[i]; v[i] = run; run += x; }
        v[nb] = run;
    }
    __syncthreads();
    if (t <= nb) boff[t] = v[t];
    if (t < nb)  cursor[t] = v[t];
}

// ---- A3: bucketed scatter of packed pairs (block-local ranks, coalescible runs) ----
__global__ void bscatter_kernel(const int* __restrict__ row, const int* __restrict__ col,
                                unsigned* __restrict__ cursor, unsigned* __restrict__ pairs,
                                int E, int nb) {
    __shared__ unsigned h[MAXB];
    __shared__ unsigned base[MAXB];
    for (int i = threadIdx.x; i < nb; i += blockDim.x) h[i] = 0;
    __syncthreads();
    int lo = blockIdx.x * CHUNK, hi = min(lo + CHUNK, E);
    for (int i = lo + threadIdx.x; i < hi; i += blockDim.x)
        atomicAdd(&h[row[i] >> 10], 1u);
    __syncthreads();
    for (int i = threadIdx.x; i < nb; i += blockDim.x) {
        base[i] = h[i] ? atomicAdd(&cursor[i], h[i]) : 0u;
        h[i] = 0;
    }
    __syncthreads();
    for (int i = lo + threadIdx.x; i < hi; i += blockDim.x) {
        int r = row[i];
        int b = r >> 10;
        unsigned p = base[b] + atomicAdd(&h[b], 1u);
        pairs[p] = ((unsigned)(r & 1023) << 20) | (unsigned)col[i];
    }
}

// ---- per-bucket degree count from pairs (replaces random global deg atomics) ----
__global__ void bdeg_kernel(const unsigned* __restrict__ boff, const unsigned* __restrict__ pairs,
                            unsigned* __restrict__ deg, int n) {
    __shared__ unsigned d[BROWS];
    int b = blockIdx.x, rbase = b * BROWS;
    int nrows = min(BROWS, n - rbase);
    for (int i = threadIdx.x; i < nrows; i += blockDim.x) d[i] = 0;
    __syncthreads();
    unsigned lo = boff[b], hi = boff[b + 1];
    for (unsigned i = lo + threadIdx.x; i < hi; i += blockDim.x)
        atomicAdd(&d[pairs[i] >> 20], 1u);
    __syncthreads();
    for (int i = threadIdx.x; i < nrows; i += blockDim.x) deg[rbase + i] = d[i];
}

// ---- inv[i] = rsqrt(deg[i] + 1)  (+1 = self loop) ----
__global__ void inv_kernel(const unsigned* __restrict__ deg, float* __restrict__ inv, int n) {
    int i = blockIdx.x * blockDim.x + threadIdx.x;
    if (i < n) inv[i] = rsqrtf((float)(deg[i] + 1u));
}

// ---- row-offset scan phase 1: per-1024-chunk sums ----
__global__ void scan1_kernel(const unsigned* __restrict__ deg, unsigned* __restrict__ part, int n) {
    __shared__ unsigned sh[256];
    int base = blockIdx.x * BROWS;
    unsigned s = 0;
    for (int i = threadIdx.x; i < BROWS; i += 256) {
        int idx = base + i;
        if (idx < n) s += deg[idx];
    }
    sh[threadIdx.x] = s;
    __syncthreads();
    for (int off = 128; off > 0; off >>= 1) {
        if (threadIdx.x < off) sh[threadIdx.x] += sh[threadIdx.x + off];
        __syncthreads();
    }
    if (threadIdx.x == 0) part[blockIdx.x] = sh[0];
}

// ---- phase 2: exclusive scan of chunk sums (parallel load, LDS serial scan) ----
__global__ void scan2_kernel(unsigned* part, int nb, unsigned* offs_last) {
    __shared__ unsigned v[MAXB];
    int t = threadIdx.x;
    if (t < nb) v[t] = part[t];
    __syncthreads();
    if (t == 0) {
        unsigned run = 0;
        for (int i = 0; i < nb; i++) { unsigned x = v[i]; v[i] = run; run += x; }
        *offs_last = run;
    }
    __syncthreads();
    if (t < nb) part[t] = v[t];
}

// ---- phase 3: per-chunk exclusive scan -> offs ----
__global__ void scan3_kernel(const unsigned* __restrict__ deg, const unsigned* __restrict__ part,
                             unsigned* __restrict__ offs, int n) {
    __shared__ unsigned sh[256];
    int t = threadIdx.x;
    int base = blockIdx.x * BROWS + t * 4;
    unsigned v[4], s = 0;
    for (int i = 0; i < 4; i++) {
        int idx = base + i;
        v[i] = (idx < n) ? deg[idx] : 0u;
        s += v[i];
    }
    sh[t] = s;
    __syncthreads();
    for (int off = 1; off < 256; off <<= 1) {
        unsigned add = (t >= off) ? sh[t - off] : 0u;
        __syncthreads();
        sh[t] += add;
        __syncthreads();
    }
    unsigned running = part[blockIdx.x] + sh[t] - s;
    for (int i = 0; i < 4; i++) {
        int idx = base + i;
        if (idx < n) { offs[idx] = running; running += v[i]; }
    }
}

// ---- fine fill: one WG per bucket, LDS cursors, CU-local writes ----
__global__ void ffill_kernel(const unsigned* __restrict__ boff, const unsigned* __restrict__ offs,
                             const unsigned* __restrict__ pairs, int* __restrict__ cols, int n) {
    __shared__ unsigned c[BROWS];
    int b = blockIdx.x, rbase = b * BROWS;
    int nrows = min(BROWS, n - rbase);
    for (int i = threadIdx.x; i < nrows; i += blockDim.x) c[i] = offs[rbase + i];
    __syncthreads();
    unsigned lo = boff[b], hi = boff[b + 1];
    for (unsigned i = lo + threadIdx.x; i < hi; i += blockDim.x) {
        unsigned pk = pairs[i];
        unsigned p = atomicAdd(&c[pk >> 20], 1u);
        cols[p] = (int)(pk & 0xFFFFFu);
    }
}

// ---- gather: wave per row, float4 lanes, 4 edges in flight, fused epilogue ----
__global__ void gather_kernel(const unsigned* __restrict__ offs, const int* __restrict__ cols,
                              const float* __restrict__ W, const float* __restrict__ inv,
                              const float* __restrict__ b, float* __restrict__ out, int n) {
    int r = blockIdx.x * 4 + (threadIdx.x >> 6);
    if (r >= n) return;
    int lane = threadIdx.x & 63;
    int sub = lane >> 4;        // which of 4 concurrent edges
    int d4 = lane & 15;         // float4 slot within the 64-wide row
    unsigned beg = offs[r], end = offs[r + 1];
    float inv_r = inv[r];
    float4 acc = make_float4(0.f, 0.f, 0.f, 0.f);
    for (unsigned k = beg + sub; k < end; k += 4) {
        int c = cols[k];
        float s = inv_r * inv[c];
        const float4 w = *(const float4*)(W + (size_t)c * EMB + d4 * 4);
        acc.x += w.x * s; acc.y += w.y * s; acc.z += w.z * s; acc.w += w.w * s;
    }
    acc.x += __shfl_xor(acc.x, 16); acc.y += __shfl_xor(acc.y, 16);
    acc.z += __shfl_xor(acc.z, 16); acc.w += __shfl_xor(acc.w, 16);
    acc.x += __shfl_xor(acc.x, 32); acc.y += __shfl_xor(acc.y, 32);
    acc.z += __shfl_xor(acc.z, 32); acc.w += __shfl_xor(acc.w, 32);
    if (sub == 0) {
        const float4 ws = *(const float4*)(W + (size_t)r * EMB + d4 * 4);
        const float4 bb = *(const float4*)(b + d4 * 4);
        float s2 = inv_r * inv_r;
        float4 o;
        o.x = fmaxf(acc.x + ws.x * s2 + bb.x, 0.f);
        o.y = fmaxf(acc.y + ws.y * s2 + bb.y, 0.f);
        o.z = fmaxf(acc.z + ws.z * s2 + bb.z, 0.f);
        o.w = fmaxf(acc.w + ws.w * s2 + bb.w, 0.f);
        *(float4*)(out + (size_t)r * EMB + d4 * 4) = o;
    }
}

extern "C" void kernel_launch(void* const* d_in, const int* in_sizes, int n_in,
                              void* d_out, int out_size, void* d_ws, size_t ws_size,
                              hipStream_t stream) {
    const int*   ue = (const int*)d_in[0];
    const int*   ie = (const int*)d_in[1];
    const float* Wu = (const float*)d_in[2];
    const float* bu = (const float*)d_in[3];
    const float* Wi = (const float*)d_in[4];
    const float* bi = (const float*)d_in[5];

    const int E_U = in_sizes[0] / 2;
    const int E_I = in_sizes[1] / 2;

    float* out_u = (float*)d_out;
    float* out_i = out_u + (size_t)NUSERS * EMB;

    const int nb_u = (NUSERS + BROWS - 1) / BROWS;  // 98
    const int nb_i = (NITEMS + BROWS - 1) / BROWS;  // 49

    // workspace layout (4-byte words)
    unsigned* w       = (unsigned*)d_ws;
    unsigned* bcnt_u  = w;            w += MAXB;      // must be zeroed (adjacent pair)
    unsigned* bcnt_i  = w;            w += MAXB;
    unsigned* boff_u  = w;            w += MAXB + 1;
    unsigned* boff_i  = w;            w += MAXB + 1;
    unsigned* curs_u  = w;            w += MAXB;
    unsigned* curs_i  = w;            w += MAXB;
    unsigned* part    = w;            w += MAXB;
    unsigned* deg_u   = w;            w += NUSERS;
    unsigned* deg_i   = w;            w += NITEMS;
    unsigned* offs_u  = w;            w += NUSERS + 1;
    unsigned* offs_i  = w;            w += NITEMS + 1;
    float*    inv_u   = (float*)w;    w += NUSERS;
    float*    inv_i   = (float*)w;    w += NITEMS;
    unsigned* pairs_u = w;            w += E_U;
    unsigned* pairs_i = w;            w += E_I;
    int*      cols_u  = (int*)w;      w += E_U;
    int*      cols_i  = (int*)w;

    hipMemsetAsync(bcnt_u, 0, 2 * MAXB * sizeof(unsigned), stream);

    const int gb_u = (E_U + CHUNK - 1) / CHUNK;  // 293
    const int gb_i = (E_I + CHUNK - 1) / CHUNK;  // 147

    // ---- user graph ----
    hist_kernel    <<<gb_u, 256, 0, stream>>>(ue, bcnt_u, E_U, nb_u);
    bscan_kernel   <<<1, 128, 0, stream>>>(bcnt_u, boff_u, curs_u, nb_u);
    bscatter_kernel<<<gb_u, 256, 0, stream>>>(ue, ue + E_U, curs_u, pairs_u, E_U, nb_u);
    bdeg_kernel    <<<nb_u, 256, 0, stream>>>(boff_u, pairs_u, deg_u, NUSERS);
    inv_kernel     <<<(NUSERS + 255) / 256, 256, 0, stream>>>(deg_u, inv_u, NUSERS);
    scan1_kernel   <<<nb_u, 256, 0, stream>>>(deg_u, part, NUSERS);
    scan2_kernel   <<<1, 128, 0, stream>>>(part, nb_u, &offs_u[NUSERS]);
    scan3_kernel   <<<nb_u, 256, 0, stream>>>(deg_u, part, offs_u, NUSERS);
    ffill_kernel   <<<nb_u, 256, 0, stream>>>(boff_u, offs_u, pairs_u, cols_u, NUSERS);
    gather_kernel  <<<(NUSERS + 3) / 4, 256, 0, stream>>>(offs_u, cols_u, Wu, inv_u, bu, out_u, NUSERS);

    // ---- item graph ----
    hist_kernel    <<<gb_i, 256, 0, stream>>>(ie, bcnt_i, E_I, nb_i);
    bscan_kernel   <<<1, 128, 0, stream>>>(bcnt_i, boff_i, curs_i, nb_i);
    bscatter_kernel<<<gb_i, 256, 0, stream>>>(ie, ie + E_I, curs_i, pairs_i, E_I, nb_i);
    bdeg_kernel    <<<nb_i, 256, 0, stream>>>(boff_i, pairs_i, deg_i, NITEMS);
    inv_kernel     <<<(NITEMS + 255) / 256, 256, 0, stream>>>(deg_i, inv_i, NITEMS);
    scan1_kernel   <<<nb_i, 256, 0, stream>>>(deg_i, part, NITEMS);
    scan2_kernel   <<<1, 128, 0, stream>>>(part, nb_i, &offs_i[NITEMS]);
    scan3_kernel   <<<nb_i, 256, 0, stream>>>(deg_i, part, offs_i, NITEMS);
    ffill_kernel   <<<nb_i, 256, 0, stream>>>(boff_i, offs_i, pairs_i, cols_i, NITEMS);
    gather_kernel  <<<(NITEMS + 3) / 4, 256, 0, stream>>>(offs_i, cols_i, Wi, inv_i, bi, out_i, NITEMS);
}

// Round 4
// 174.259 us; speedup vs baseline: 2.9413x; 1.3822x over previous
//
#include <hip/hip_runtime.h>
#include <hip/hip_fp16.h>

#define NUSERS 100000
#define NITEMS 50000
#define EMB 64
#define BROWS 1024      // rows per bucket
#define CHUNK 4096      // edges per block in bucket passes
#define MAXB 128        // max buckets (user: 98, item: 49)
#define NB_U ((NUSERS + BROWS - 1) / BROWS)   // 98
#define NB_I ((NITEMS + BROWS - 1) / BROWS)   // 49

// packed pair: (local_row << 20) | col   (local_row < 1024, col < 2^17)

// ---- A1 fused: coarse bucket histogram for both graphs ----
__global__ void hist2_kernel(const int* __restrict__ rowU, const int* __restrict__ rowI,
                             unsigned* __restrict__ bcntU, unsigned* __restrict__ bcntI,
                             int EU, int EI, int gbU) {
    __shared__ unsigned h[MAXB];
    const int* row; unsigned* bcnt; int E, blk, nb;
    if ((int)blockIdx.x < gbU) { row = rowU; bcnt = bcntU; E = EU; blk = blockIdx.x; nb = NB_U; }
    else                       { row = rowI; bcnt = bcntI; E = EI; blk = blockIdx.x - gbU; nb = NB_I; }
    for (int i = threadIdx.x; i < nb; i += blockDim.x) h[i] = 0;
    __syncthreads();
    int lo = blk * CHUNK, hi = min(lo + CHUNK, E);
    for (int i = lo + threadIdx.x; i < hi; i += blockDim.x)
        atomicAdd(&h[row[i] >> 10], 1u);
    __syncthreads();
    for (int i = threadIdx.x; i < nb; i += blockDim.x)
        if (h[i]) atomicAdd(&bcnt[i], h[i]);
}

// ---- A2 fused: exclusive scan of bucket counts -> boff, cursors (2 blocks) ----
__global__ void bscan2_kernel(const unsigned* __restrict__ bcntU, const unsigned* __restrict__ bcntI,
                              unsigned* __restrict__ boffU, unsigned* __restrict__ boffI,
                              unsigned* __restrict__ cursU, unsigned* __restrict__ cursI) {
    __shared__ unsigned v[MAXB + 1];
    const unsigned* bcnt; unsigned* boff; unsigned* cur; int nb;
    if (blockIdx.x == 0) { bcnt = bcntU; boff = boffU; cur = cursU; nb = NB_U; }
    else                 { bcnt = bcntI; boff = boffI; cur = cursI; nb = NB_I; }
    int t = threadIdx.x;
    if (t < nb) v[t] = bcnt[t];
    __syncthreads();
    if (t == 0) {
        unsigned run = 0;
        for (int i = 0; i < nb; i++) { unsigned x = v[i]; v[i] = run; run += x; }
        v[nb] = run;
    }
    __syncthreads();
    if (t <= nb) boff[t] = v[t];
    if (t < nb)  cur[t] = v[t];
}

// ---- A3 fused: bucketed scatter of packed pairs ----
__global__ void bscatter2_kernel(const int* __restrict__ rowU, const int* __restrict__ rowI,
                                 unsigned* __restrict__ cursU, unsigned* __restrict__ cursI,
                                 unsigned* __restrict__ pairsU, unsigned* __restrict__ pairsI,
                                 int EU, int EI, int gbU) {
    __shared__ unsigned h[MAXB];
    __shared__ unsigned base[MAXB];
    const int* row; const int* col; unsigned* cursor; unsigned* pairs; int E, blk, nb;
    if ((int)blockIdx.x < gbU) { row = rowU; col = rowU + EU; cursor = cursU; pairs = pairsU; E = EU; blk = blockIdx.x; nb = NB_U; }
    else                       { row = rowI; col = rowI + EI; cursor = cursI; pairs = pairsI; E = EI; blk = blockIdx.x - gbU; nb = NB_I; }
    for (int i = threadIdx.x; i < nb; i += blockDim.x) h[i] = 0;
    __syncthreads();
    int lo = blk * CHUNK, hi = min(lo + CHUNK, E);
    for (int i = lo + threadIdx.x; i < hi; i += blockDim.x)
        atomicAdd(&h[row[i] >> 10], 1u);
    __syncthreads();
    for (int i = threadIdx.x; i < nb; i += blockDim.x) {
        base[i] = h[i] ? atomicAdd(&cursor[i], h[i]) : 0u;
        h[i] = 0;
    }
    __syncthreads();
    for (int i = lo + threadIdx.x; i < hi; i += blockDim.x) {
        int r = row[i];
        int b = r >> 10;
        unsigned p = base[b] + atomicAdd(&h[b], 1u);
        pairs[p] = ((unsigned)(r & 1023) << 20) | (unsigned)col[i];
    }
}

// ---- fused: per-bucket degree + inv + bucket-sum (part) for both graphs ----
__global__ void bdeginv2_kernel(const unsigned* __restrict__ boffU, const unsigned* __restrict__ boffI,
                                const unsigned* __restrict__ pairsU, const unsigned* __restrict__ pairsI,
                                unsigned* __restrict__ degU, unsigned* __restrict__ degI,
                                float* __restrict__ invU, float* __restrict__ invI,
                                unsigned* __restrict__ partU, unsigned* __restrict__ partI) {
    __shared__ unsigned d[BROWS];
    __shared__ unsigned red[256];
    const unsigned* boff; const unsigned* pairs; unsigned* deg; float* inv; unsigned* part; int n, b;
    if ((int)blockIdx.x < NB_U) { boff = boffU; pairs = pairsU; deg = degU; inv = invU; part = partU; n = NUSERS; b = blockIdx.x; }
    else                        { boff = boffI; pairs = pairsI; deg = degI; inv = invI; part = partI; n = NITEMS; b = blockIdx.x - NB_U; }
    int rbase = b * BROWS;
    int nrows = min(BROWS, n - rbase);
    for (int i = threadIdx.x; i < nrows; i += blockDim.x) d[i] = 0;
    __syncthreads();
    unsigned lo = boff[b], hi = boff[b + 1];
    for (unsigned i = lo + threadIdx.x; i < hi; i += blockDim.x)
        atomicAdd(&d[pairs[i] >> 20], 1u);
    __syncthreads();
    unsigned s = 0;
    for (int i = threadIdx.x; i < nrows; i += blockDim.x) {
        unsigned v = d[i];
        deg[rbase + i] = v;
        inv[rbase + i] = rsqrtf((float)(v + 1u));
        s += v;
    }
    red[threadIdx.x] = s;
    __syncthreads();
    for (int off = 128; off > 0; off >>= 1) {
        if ((int)threadIdx.x < off) red[threadIdx.x] += red[threadIdx.x + off];
        __syncthreads();
    }
    if (threadIdx.x == 0) part[b] = red[0];
}

// ---- fused: exclusive scan of per-bucket sums (2 blocks) ----
__global__ void scan2b_kernel(unsigned* __restrict__ partU, unsigned* __restrict__ partI,
                              unsigned* __restrict__ offsU_last, unsigned* __restrict__ offsI_last) {
    __shared__ unsigned v[MAXB];
    unsigned* part; unsigned* last; int nb;
    if (blockIdx.x == 0) { part = partU; last = offsU_last; nb = NB_U; }
    else                 { part = partI; last = offsI_last; nb = NB_I; }
    int t = threadIdx.x;
    if (t < nb) v[t] = part[t];
    __syncthreads();
    if (t == 0) {
        unsigned run = 0;
        for (int i = 0; i < nb; i++) { unsigned x = v[i]; v[i] = run; run += x; }
        *last = run;
    }
    __syncthreads();
    if (t < nb) part[t] = v[t];
}

// ---- fused: per-chunk exclusive scan of degrees -> row offsets ----
__global__ void scan3b_kernel(const unsigned* __restrict__ degU, const unsigned* __restrict__ degI,
                              const unsigned* __restrict__ partU, const unsigned* __restrict__ partI,
                              unsigned* __restrict__ offsU, unsigned* __restrict__ offsI) {
    __shared__ unsigned sh[256];
    const unsigned* deg; const unsigned* part; unsigned* offs; int n, b;
    if ((int)blockIdx.x < NB_U) { deg = degU; part = partU; offs = offsU; n = NUSERS; b = blockIdx.x; }
    else                        { deg = degI; part = partI; offs = offsI; n = NITEMS; b = blockIdx.x - NB_U; }
    int t = threadIdx.x;
    int base = b * BROWS + t * 4;
    unsigned v[4], s = 0;
    for (int i = 0; i < 4; i++) {
        int idx = base + i;
        v[i] = (idx < n) ? deg[idx] : 0u;
        s += v[i];
    }
    sh[t] = s;
    __syncthreads();
    for (int off = 1; off < 256; off <<= 1) {
        unsigned add = (t >= off) ? sh[t - off] : 0u;
        __syncthreads();
        sh[t] += add;
        __syncthreads();
    }
    unsigned running = part[b] + sh[t] - s;
    for (int i = 0; i < 4; i++) {
        int idx = base + i;
        if (idx < n) { offs[idx] = running; running += v[i]; }
    }
}

// ---- fused fine fill: one WG per bucket, LDS cursors ----
__global__ void ffill2_kernel(const unsigned* __restrict__ boffU, const unsigned* __restrict__ boffI,
                              const unsigned* __restrict__ offsU, const unsigned* __restrict__ offsI,
                              const unsigned* __restrict__ pairsU, const unsigned* __restrict__ pairsI,
                              int* __restrict__ colsU, int* __restrict__ colsI) {
    __shared__ unsigned c[BROWS];
    const unsigned* boff; const unsigned* offs; const unsigned* pairs; int* cols; int n, b;
    if ((int)blockIdx.x < NB_U) { boff = boffU; offs = offsU; pairs = pairsU; cols = colsU; n = NUSERS; b = blockIdx.x; }
    else                        { boff = boffI; offs = offsI; pairs = pairsI; cols = colsI; n = NITEMS; b = blockIdx.x - NB_U; }
    int rbase = b * BROWS;
    int nrows = min(BROWS, n - rbase);
    for (int i = threadIdx.x; i < nrows; i += blockDim.x) c[i] = offs[rbase + i];
    __syncthreads();
    unsigned lo = boff[b], hi = boff[b + 1];
    for (unsigned i = lo + threadIdx.x; i < hi; i += blockDim.x) {
        unsigned pk = pairs[i];
        unsigned p = atomicAdd(&c[pk >> 20], 1u);
        cols[p] = (int)(pk & 0xFFFFFu);
    }
}

// ---- fused: W*inv[row] -> f16 copies (pre-scaled by source-node norm) ----
__global__ void tohalf2_kernel(const float* __restrict__ WU, const float* __restrict__ WI,
                               const float* __restrict__ invU, const float* __restrict__ invI,
                               __half* __restrict__ WhU, __half* __restrict__ WhI) {
    const int totU = NUSERS * EMB / 4;
    const int totI = NITEMS * EMB / 4;
    int i = blockIdx.x * 256 + threadIdx.x;
    const float* W; const float* inv; __half* Wh;
    if (i < totU)             { W = WU; inv = invU; Wh = WhU; }
    else if (i < totU + totI) { i -= totU; W = WI; inv = invI; Wh = WhI; }
    else return;
    int r = i >> 4;                 // 16 float4s per row
    float s = inv[r];
    float4 w = ((const float4*)W)[i];
    __half2 h0 = __floats2half2_rn(w.x * s, w.y * s);
    __half2 h1 = __floats2half2_rn(w.z * s, w.w * s);
    ((__half2*)Wh)[2 * i]     = h0;
    ((__half2*)Wh)[2 * i + 1] = h1;
}

// ---- fused gather, f16 pre-scaled W: out = relu((Σ Wh[c] + Wh[r]) * inv_r + b) ----
__global__ void gather2h_kernel(const unsigned* __restrict__ offsU, const unsigned* __restrict__ offsI,
                                const int* __restrict__ colsU, const int* __restrict__ colsI,
                                const __half* __restrict__ WhU, const __half* __restrict__ WhI,
                                const float* __restrict__ bU, const float* __restrict__ bI,
                                const float* __restrict__ invU, const float* __restrict__ invI,
                                float* __restrict__ outU, float* __restrict__ outI, int gbU) {
    const unsigned* offs; const int* cols; const __half* Wh; const float* bb; const float* inv;
    float* out; int n, r0;
    if ((int)blockIdx.x < gbU) { offs = offsU; cols = colsU; Wh = WhU; bb = bU; inv = invU; out = outU; n = NUSERS; r0 = blockIdx.x * 4; }
    else                       { offs = offsI; cols = colsI; Wh = WhI; bb = bI; inv = invI; out = outI; n = NITEMS; r0 = (blockIdx.x - gbU) * 4; }
    int r = r0 + (threadIdx.x >> 6);
    if (r >= n) return;
    int lane = threadIdx.x & 63;
    int sub = lane >> 4;
    int d4 = lane & 15;
    unsigned beg = offs[r], end = offs[r + 1];
    float4 acc = make_float4(0.f, 0.f, 0.f, 0.f);
    for (unsigned k = beg + sub; k < end; k += 4) {
        int c = cols[k];
        union { float2 f; __half2 h[2]; } u;
        u.f = *(const float2*)(Wh + (size_t)c * EMB + d4 * 4);
        float2 a = __half22float2(u.h[0]);
        float2 b2 = __half22float2(u.h[1]);
        acc.x += a.x; acc.y += a.y; acc.z += b2.x; acc.w += b2.y;
    }
    acc.x += __shfl_xor(acc.x, 16); acc.y += __shfl_xor(acc.y, 16);
    acc.z += __shfl_xor(acc.z, 16); acc.w += __shfl_xor(acc.w, 16);
    acc.x += __shfl_xor(acc.x, 32); acc.y += __shfl_xor(acc.y, 32);
    acc.z += __shfl_xor(acc.z, 32); acc.w += __shfl_xor(acc.w, 32);
    if (sub == 0) {
        float inv_r = inv[r];
        union { float2 f; __half2 h[2]; } us;
        us.f = *(const float2*)(Wh + (size_t)r * EMB + d4 * 4);   // self loop: Wh[r]*inv_r = W[r]*inv_r^2
        float2 sa = __half22float2(us.h[0]);
        float2 sb = __half22float2(us.h[1]);
        const float4 bv = *(const float4*)(bb + d4 * 4);
        float4 o;
        o.x = fmaxf((acc.x + sa.x) * inv_r + bv.x, 0.f);
        o.y = fmaxf((acc.y + sa.y) * inv_r + bv.y, 0.f);
        o.z = fmaxf((acc.z + sb.x) * inv_r + bv.z, 0.f);
        o.w = fmaxf((acc.w + sb.y) * inv_r + bv.w, 0.f);
        *(float4*)(out + (size_t)r * EMB + d4 * 4) = o;
    }
}

// ---- fused gather, f32 fallback (if workspace too small for f16 copies) ----
__global__ void gather2f_kernel(const unsigned* __restrict__ offsU, const unsigned* __restrict__ offsI,
                                const int* __restrict__ colsU, const int* __restrict__ colsI,
                                const float* __restrict__ WU, const float* __restrict__ WI,
                                const float* __restrict__ bU, const float* __restrict__ bI,
                                const float* __restrict__ invU, const float* __restrict__ invI,
                                float* __restrict__ outU, float* __restrict__ outI, int gbU) {
    const unsigned* offs; const int* cols; const float* W; const float* bb; const float* inv;
    float* out; int n, r0;
    if ((int)blockIdx.x < gbU) { offs = offsU; cols = colsU; W = WU; bb = bU; inv = invU; out = outU; n = NUSERS; r0 = blockIdx.x * 4; }
    else                       { offs = offsI; cols = colsI; W = WI; bb = bI; inv = invI; out = outI; n = NITEMS; r0 = (blockIdx.x - gbU) * 4; }
    int r = r0 + (threadIdx.x >> 6);
    if (r >= n) return;
    int lane = threadIdx.x & 63;
    int sub = lane >> 4;
    int d4 = lane & 15;
    unsigned beg = offs[r], end = offs[r + 1];
    float inv_r = inv[r];
    float4 acc = make_float4(0.f, 0.f, 0.f, 0.f);
    for (unsigned k = beg + sub; k < end; k += 4) {
        int c = cols[k];
        float s = inv[c];
        const float4 w = *(const float4*)(W + (size_t)c * EMB + d4 * 4);
        acc.x += w.x * s; acc.y += w.y * s; acc.z += w.z * s; acc.w += w.w * s;
    }
    acc.x += __shfl_xor(acc.x, 16); acc.y += __shfl_xor(acc.y, 16);
    acc.z += __shfl_xor(acc.z, 16); acc.w += __shfl_xor(acc.w, 16);
    acc.x += __shfl_xor(acc.x, 32); acc.y += __shfl_xor(acc.y, 32);
    acc.z += __shfl_xor(acc.z, 32); acc.w += __shfl_xor(acc.w, 32);
    if (sub == 0) {
        const float4 ws = *(const float4*)(W + (size_t)r * EMB + d4 * 4);
        const float4 bv = *(const float4*)(bb + d4 * 4);
        float4 o;
        o.x = fmaxf((acc.x + ws.x * inv_r) * inv_r + bv.x, 0.f);
        o.y = fmaxf((acc.y + ws.y * inv_r) * inv_r + bv.y, 0.f);
        o.z = fmaxf((acc.z + ws.z * inv_r) * inv_r + bv.z, 0.f);
        o.w = fmaxf((acc.w + ws.w * inv_r) * inv_r + bv.w, 0.f);
        *(float4*)(out + (size_t)r * EMB + d4 * 4) = o;
    }
}

extern "C" void kernel_launch(void* const* d_in, const int* in_sizes, int n_in,
                              void* d_out, int out_size, void* d_ws, size_t ws_size,
                              hipStream_t stream) {
    const int*   ue = (const int*)d_in[0];
    const int*   ie = (const int*)d_in[1];
    const float* Wu = (const float*)d_in[2];
    const float* bu = (const float*)d_in[3];
    const float* Wi = (const float*)d_in[4];
    const float* bi = (const float*)d_in[5];

    const int E_U = in_sizes[0] / 2;
    const int E_I = in_sizes[1] / 2;

    float* out_u = (float*)d_out;
    float* out_i = out_u + (size_t)NUSERS * EMB;

    // workspace layout (4-byte words)
    unsigned* w       = (unsigned*)d_ws;
    unsigned* bcnt_u  = w;            w += MAXB;      // zeroed (adjacent pair)
    unsigned* bcnt_i  = w;            w += MAXB;
    unsigned* boff_u  = w;            w += MAXB + 1;
    unsigned* boff_i  = w;            w += MAXB + 1;
    unsigned* curs_u  = w;            w += MAXB;
    unsigned* curs_i  = w;            w += MAXB;
    unsigned* part_u  = w;            w += MAXB;
    unsigned* part_i  = w;            w += MAXB;
    unsigned* deg_u   = w;            w += NUSERS;
    unsigned* deg_i   = w;            w += NITEMS;
    unsigned* offs_u  = w;            w += NUSERS + 1;
    unsigned* offs_i  = w;            w += NITEMS + 1;
    float*    inv_u   = (float*)w;    w += NUSERS;
    float*    inv_i   = (float*)w;    w += NITEMS;
    unsigned* pairs_u = w;            w += E_U;
    unsigned* pairs_i = w;            w += E_I;
    int*      cols_u  = (int*)w;      w += E_U;
    int*      cols_i  = (int*)w;      w += E_I;
    w += (size_t)(-(intptr_t)(w - (unsigned*)d_ws)) & 3;   // align to 16 B
    __half*   wh_u    = (__half*)w;   w += (size_t)NUSERS * EMB / 2;
    __half*   wh_i    = (__half*)w;   w += (size_t)NITEMS * EMB / 2;

    const size_t need_bytes = (size_t)((char*)w - (char*)d_ws);
    const bool use_half = (ws_size >= need_bytes);

    hipMemsetAsync(bcnt_u, 0, 2 * MAXB * sizeof(unsigned), stream);

    const int gb_u = (E_U + CHUNK - 1) / CHUNK;  // 293
    const int gb_i = (E_I + CHUNK - 1) / CHUNK;  // 147
    const int gg_u = (NUSERS + 3) / 4;           // 25000
    const int gg_i = (NITEMS + 3) / 4;           // 12500

    hist2_kernel    <<<gb_u + gb_i, 256, 0, stream>>>(ue, ie, bcnt_u, bcnt_i, E_U, E_I, gb_u);
    bscan2_kernel   <<<2, 128, 0, stream>>>(bcnt_u, bcnt_i, boff_u, boff_i, curs_u, curs_i);
    bscatter2_kernel<<<gb_u + gb_i, 256, 0, stream>>>(ue, ie, curs_u, curs_i, pairs_u, pairs_i, E_U, E_I, gb_u);
    bdeginv2_kernel <<<NB_U + NB_I, 256, 0, stream>>>(boff_u, boff_i, pairs_u, pairs_i,
                                                      deg_u, deg_i, inv_u, inv_i, part_u, part_i);
    scan2b_kernel   <<<2, 128, 0, stream>>>(part_u, part_i, &offs_u[NUSERS], &offs_i[NITEMS]);
    scan3b_kernel   <<<NB_U + NB_I, 256, 0, stream>>>(deg_u, deg_i, part_u, part_i, offs_u, offs_i);
    ffill2_kernel   <<<NB_U + NB_I, 256, 0, stream>>>(boff_u, boff_i, offs_u, offs_i,
                                                      pairs_u, pairs_i, cols_u, cols_i);
    if (use_half) {
        const int tot4 = (NUSERS + NITEMS) * EMB / 4;
        tohalf2_kernel <<<(tot4 + 255) / 256, 256, 0, stream>>>(Wu, Wi, inv_u, inv_i, wh_u, wh_i);
        gather2h_kernel<<<gg_u + gg_i, 256, 0, stream>>>(offs_u, offs_i, cols_u, cols_i,
                                                         wh_u, wh_i, bu, bi, inv_u, inv_i,
                                                         out_u, out_i, gg_u);
    } else {
        gather2f_kernel<<<gg_u + gg_i, 256, 0, stream>>>(offs_u, offs_i, cols_u, cols_i,
                                                         Wu, Wi, bu, bi, inv_u, inv_i,
                                                         out_u, out_i, gg_u);
    }
}

// Round 5
// 153.534 us; speedup vs baseline: 3.3383x; 1.1350x over previous
//
#include <hip/hip_runtime.h>
#include <hip/hip_fp16.h>

#define NUSERS 100000
#define NITEMS 50000
#define EMB 64
#define BROWS 1024      // rows per bucket
#define CHUNK 4096      // edges per block in bucket passes
#define MAXB 128        // max buckets (user: 98, item: 49)
#define NB_U ((NUSERS + BROWS - 1) / BROWS)   // 98
#define NB_I ((NITEMS + BROWS - 1) / BROWS)   // 49

// packed pair: (local_row << 20) | col   (local_row < 1024, col < 2^17)

// ---- A1 fused: coarse bucket histogram for both graphs ----
__global__ void hist2_kernel(const int* __restrict__ rowU, const int* __restrict__ rowI,
                             unsigned* __restrict__ bcntU, unsigned* __restrict__ bcntI,
                             int EU, int EI, int gbU) {
    __shared__ unsigned h[MAXB];
    const int* row; unsigned* bcnt; int E, blk, nb;
    if ((int)blockIdx.x < gbU) { row = rowU; bcnt = bcntU; E = EU; blk = blockIdx.x; nb = NB_U; }
    else                       { row = rowI; bcnt = bcntI; E = EI; blk = blockIdx.x - gbU; nb = NB_I; }
    for (int i = threadIdx.x; i < nb; i += blockDim.x) h[i] = 0;
    __syncthreads();
    int lo = blk * CHUNK, hi = min(lo + CHUNK, E);
    for (int i = lo + threadIdx.x; i < hi; i += blockDim.x)
        atomicAdd(&h[row[i] >> 10], 1u);
    __syncthreads();
    for (int i = threadIdx.x; i < nb; i += blockDim.x)
        if (h[i]) atomicAdd(&bcnt[i], h[i]);
}

// ---- A2+A3 fused: per-block redundant scan of bcnt + bucketed scatter ----
// cursor allocation via zero-initialized claimed[]: pos = boff[b] + atomicAdd(&claimed[b], h[b])
__global__ void bscatter2_kernel(const int* __restrict__ rowU, const int* __restrict__ rowI,
                                 const unsigned* __restrict__ bcntU, const unsigned* __restrict__ bcntI,
                                 unsigned* __restrict__ claimU, unsigned* __restrict__ claimI,
                                 unsigned* __restrict__ boffU, unsigned* __restrict__ boffI,
                                 unsigned* __restrict__ pairsU, unsigned* __restrict__ pairsI,
                                 int EU, int EI, int gbU) {
    __shared__ unsigned h[MAXB];
    __shared__ unsigned base[MAXB];
    __shared__ unsigned bl[MAXB + 1];
    const int* row; const int* col; const unsigned* bcnt; unsigned* claimed;
    unsigned* boff; unsigned* pairs; int E, blk, nb;
    if ((int)blockIdx.x < gbU) {
        row = rowU; col = rowU + EU; bcnt = bcntU; claimed = claimU; boff = boffU;
        pairs = pairsU; E = EU; blk = blockIdx.x; nb = NB_U;
    } else {
        row = rowI; col = rowI + EI; bcnt = bcntI; claimed = claimI; boff = boffI;
        pairs = pairsI; E = EI; blk = blockIdx.x - gbU; nb = NB_I;
    }
    int t = threadIdx.x;
    for (int i = t; i < nb; i += blockDim.x) h[i] = 0;
    if (t < nb) bl[t] = bcnt[t];
    __syncthreads();
    if (t == 0) {                       // serial exclusive scan in LDS (nb <= 98)
        unsigned run = 0;
        for (int i = 0; i < nb; i++) { unsigned x = bl[i]; bl[i] = run; run += x; }
        bl[nb] = run;
    }
    __syncthreads();
    if (blk == 0 && t <= nb) boff[t] = bl[t];   // designated writer per graph
    int lo = blk * CHUNK, hi = min(lo + CHUNK, E);
    for (int i = lo + t; i < hi; i += blockDim.x)
        atomicAdd(&h[row[i] >> 10], 1u);
    __syncthreads();
    for (int i = t; i < nb; i += blockDim.x) {
        base[i] = h[i] ? (bl[i] + atomicAdd(&claimed[i], h[i])) : 0u;
        h[i] = 0;
    }
    __syncthreads();
    for (int i = lo + t; i < hi; i += blockDim.x) {
        int r = row[i];
        int b = r >> 10;
        unsigned p = base[b] + atomicAdd(&h[b], 1u);
        pairs[p] = ((unsigned)(r & 1023) << 20) | (unsigned)col[i];
    }
}

// ---- fused: per-bucket degree + inv + bucket-sum (part) for both graphs ----
__global__ void bdeginv2_kernel(const unsigned* __restrict__ boffU, const unsigned* __restrict__ boffI,
                                const unsigned* __restrict__ pairsU, const unsigned* __restrict__ pairsI,
                                unsigned* __restrict__ degU, unsigned* __restrict__ degI,
                                float* __restrict__ invU, float* __restrict__ invI,
                                unsigned* __restrict__ partU, unsigned* __restrict__ partI) {
    __shared__ unsigned d[BROWS];
    __shared__ unsigned red[256];
    const unsigned* boff; const unsigned* pairs; unsigned* deg; float* inv; unsigned* part; int n, b;
    if ((int)blockIdx.x < NB_U) { boff = boffU; pairs = pairsU; deg = degU; inv = invU; part = partU; n = NUSERS; b = blockIdx.x; }
    else                        { boff = boffI; pairs = pairsI; deg = degI; inv = invI; part = partI; n = NITEMS; b = blockIdx.x - NB_U; }
    int rbase = b * BROWS;
    int nrows = min(BROWS, n - rbase);
    for (int i = threadIdx.x; i < nrows; i += blockDim.x) d[i] = 0;
    __syncthreads();
    unsigned lo = boff[b], hi = boff[b + 1];
    for (unsigned i = lo + threadIdx.x; i < hi; i += blockDim.x)
        atomicAdd(&d[pairs[i] >> 20], 1u);
    __syncthreads();
    unsigned s = 0;
    for (int i = threadIdx.x; i < nrows; i += blockDim.x) {
        unsigned v = d[i];
        deg[rbase + i] = v;
        inv[rbase + i] = rsqrtf((float)(v + 1u));
        s += v;
    }
    red[threadIdx.x] = s;
    __syncthreads();
    for (int off = 128; off > 0; off >>= 1) {
        if ((int)threadIdx.x < off) red[threadIdx.x] += red[threadIdx.x + off];
        __syncthreads();
    }
    if (threadIdx.x == 0) part[b] = red[0];
}

// ---- fused: part-scan + per-bucket deg scan -> offs, + fine fill, one pass ----
__global__ void scan3ffill_kernel(const unsigned* __restrict__ degU, const unsigned* __restrict__ degI,
                                  const unsigned* __restrict__ partU, const unsigned* __restrict__ partI,
                                  const unsigned* __restrict__ boffU, const unsigned* __restrict__ boffI,
                                  const unsigned* __restrict__ pairsU, const unsigned* __restrict__ pairsI,
                                  unsigned* __restrict__ offsU, unsigned* __restrict__ offsI,
                                  int* __restrict__ colsU, int* __restrict__ colsI) {
    __shared__ unsigned sh[256];
    __shared__ unsigned c[BROWS];
    __shared__ unsigned pt[MAXB + 1];
    const unsigned* deg; const unsigned* part; const unsigned* boff; const unsigned* pairs;
    unsigned* offs; int* cols; int n, b, nb;
    if ((int)blockIdx.x < NB_U) { deg = degU; part = partU; boff = boffU; pairs = pairsU; offs = offsU; cols = colsU; n = NUSERS; b = blockIdx.x; nb = NB_U; }
    else                        { deg = degI; part = partI; boff = boffI; pairs = pairsI; offs = offsI; cols = colsI; n = NITEMS; b = blockIdx.x - NB_U; nb = NB_I; }
    int t = threadIdx.x;
    if (t < nb) pt[t] = part[t];
    __syncthreads();
    if (t == 0) {                       // full exclusive scan of bucket sums in LDS
        unsigned run = 0;
        for (int i = 0; i < nb; i++) { unsigned x = pt[i]; pt[i] = run; run += x; }
        pt[nb] = run;
    }
    __syncthreads();
    unsigned pbase = pt[b];
    if (b == nb - 1 && t == 0) offs[n] = pt[nb];
    // block scan of this bucket's degrees
    int rbase = b * BROWS;
    int base = rbase + t * 4;
    unsigned v[4], s = 0;
    for (int i = 0; i < 4; i++) {
        int idx = base + i;
        v[i] = (idx < n) ? deg[idx] : 0u;
        s += v[i];
    }
    sh[t] = s;
    __syncthreads();
    for (int off = 1; off < 256; off <<= 1) {
        unsigned add = (t >= off) ? sh[t - off] : 0u;
        __syncthreads();
        sh[t] += add;
        __syncthreads();
    }
    unsigned running = pbase + sh[t] - s;
    for (int i = 0; i < 4; i++) {
        int idx = base + i;
        if (idx < n) { offs[idx] = running; c[t * 4 + i] = running; running += v[i]; }
    }
    __syncthreads();
    // fine fill from pairs via LDS cursors
    unsigned lo = boff[b], hi = boff[b + 1];
    for (unsigned i = lo + t; i < hi; i += blockDim.x) {
        unsigned pk = pairs[i];
        unsigned p = atomicAdd(&c[pk >> 20], 1u);
        cols[p] = (int)(pk & 0xFFFFFu);
    }
}

// ---- fused: W*inv[row] -> f16 copies (pre-scaled by source-node norm) ----
__global__ void tohalf2_kernel(const float* __restrict__ WU, const float* __restrict__ WI,
                               const float* __restrict__ invU, const float* __restrict__ invI,
                               __half* __restrict__ WhU, __half* __restrict__ WhI) {
    const int totU = NUSERS * EMB / 4;
    const int totI = NITEMS * EMB / 4;
    int i = blockIdx.x * 256 + threadIdx.x;
    const float* W; const float* inv; __half* Wh;
    if (i < totU)             { W = WU; inv = invU; Wh = WhU; }
    else if (i < totU + totI) { i -= totU; W = WI; inv = invI; Wh = WhI; }
    else return;
    int r = i >> 4;                 // 16 float4s per row
    float s = inv[r];
    float4 w = ((const float4*)W)[i];
    __half2 h0 = __floats2half2_rn(w.x * s, w.y * s);
    __half2 h1 = __floats2half2_rn(w.z * s, w.w * s);
    ((__half2*)Wh)[2 * i]     = h0;
    ((__half2*)Wh)[2 * i + 1] = h1;
}

// ---- fused gather, f16, 8 edges in flight (8 lanes x 16B per edge) ----
__global__ void gather2h_kernel(const unsigned* __restrict__ offsU, const unsigned* __restrict__ offsI,
                                const int* __restrict__ colsU, const int* __restrict__ colsI,
                                const __half* __restrict__ WhU, const __half* __restrict__ WhI,
                                const float* __restrict__ bU, const float* __restrict__ bI,
                                const float* __restrict__ invU, const float* __restrict__ invI,
                                float* __restrict__ outU, float* __restrict__ outI, int gbU) {
    const unsigned* offs; const int* cols; const __half* Wh; const float* bb; const float* inv;
    float* out; int n, r0;
    if ((int)blockIdx.x < gbU) { offs = offsU; cols = colsU; Wh = WhU; bb = bU; inv = invU; out = outU; n = NUSERS; r0 = blockIdx.x * 4; }
    else                       { offs = offsI; cols = colsI; Wh = WhI; bb = bI; inv = invI; out = outI; n = NITEMS; r0 = (blockIdx.x - gbU) * 4; }
    int r = r0 + (threadIdx.x >> 6);
    if (r >= n) return;
    int lane = threadIdx.x & 63;
    int sub = lane >> 3;        // 0..7: which of 8 concurrent edges
    int d8  = lane & 7;         // 16B slot within the 128B f16 row
    unsigned beg = offs[r], end = offs[r + 1];
    float acc[8] = {0.f, 0.f, 0.f, 0.f, 0.f, 0.f, 0.f, 0.f};
    for (unsigned k = beg + sub; k < end; k += 8) {
        int c = cols[k];
        union { float4 f; __half2 h[4]; } u;
        u.f = *(const float4*)(Wh + (size_t)c * EMB + d8 * 8);
        #pragma unroll
        for (int j = 0; j < 4; j++) {
            float2 tv = __half22float2(u.h[j]);
            acc[2 * j]     += tv.x;
            acc[2 * j + 1] += tv.y;
        }
    }
    #pragma unroll
    for (int m = 8; m < 64; m <<= 1) {
        #pragma unroll
        for (int j = 0; j < 8; j++) acc[j] += __shfl_xor(acc[j], m);
    }
    if (sub == 0) {
        float inv_r = inv[r];
        union { float4 f; __half2 h[4]; } us;
        us.f = *(const float4*)(Wh + (size_t)r * EMB + d8 * 8);   // self loop: Wh[r]*inv_r = W[r]*inv_r^2
        const float4 bv0 = *(const float4*)(bb + d8 * 8);
        const float4 bv1 = *(const float4*)(bb + d8 * 8 + 4);
        float sf[8];
        #pragma unroll
        for (int j = 0; j < 4; j++) {
            float2 tv = __half22float2(us.h[j]);
            sf[2 * j] = tv.x; sf[2 * j + 1] = tv.y;
        }
        float4 o0, o1;
        o0.x = fmaxf((acc[0] + sf[0]) * inv_r + bv0.x, 0.f);
        o0.y = fmaxf((acc[1] + sf[1]) * inv_r + bv0.y, 0.f);
        o0.z = fmaxf((acc[2] + sf[2]) * inv_r + bv0.z, 0.f);
        o0.w = fmaxf((acc[3] + sf[3]) * inv_r + bv0.w, 0.f);
        o1.x = fmaxf((acc[4] + sf[4]) * inv_r + bv1.x, 0.f);
        o1.y = fmaxf((acc[5] + sf[5]) * inv_r + bv1.y, 0.f);
        o1.z = fmaxf((acc[6] + sf[6]) * inv_r + bv1.z, 0.f);
        o1.w = fmaxf((acc[7] + sf[7]) * inv_r + bv1.w, 0.f);
        *(float4*)(out + (size_t)r * EMB + d8 * 8)     = o0;
        *(float4*)(out + (size_t)r * EMB + d8 * 8 + 4) = o1;
    }
}

// ---- fused gather, f32 fallback (if workspace too small for f16 copies) ----
__global__ void gather2f_kernel(const unsigned* __restrict__ offsU, const unsigned* __restrict__ offsI,
                                const int* __restrict__ colsU, const int* __restrict__ colsI,
                                const float* __restrict__ WU, const float* __restrict__ WI,
                                const float* __restrict__ bU, const float* __restrict__ bI,
                                const float* __restrict__ invU, const float* __restrict__ invI,
                                float* __restrict__ outU, float* __restrict__ outI, int gbU) {
    const unsigned* offs; const int* cols; const float* W; const float* bb; const float* inv;
    float* out; int n, r0;
    if ((int)blockIdx.x < gbU) { offs = offsU; cols = colsU; W = WU; bb = bU; inv = invU; out = outU; n = NUSERS; r0 = blockIdx.x * 4; }
    else                       { offs = offsI; cols = colsI; W = WI; bb = bI; inv = invI; out = outI; n = NITEMS; r0 = (blockIdx.x - gbU) * 4; }
    int r = r0 + (threadIdx.x >> 6);
    if (r >= n) return;
    int lane = threadIdx.x & 63;
    int sub = lane >> 4;
    int d4 = lane & 15;
    unsigned beg = offs[r], end = offs[r + 1];
    float inv_r = inv[r];
    float4 acc = make_float4(0.f, 0.f, 0.f, 0.f);
    for (unsigned k = beg + sub; k < end; k += 4) {
        int c = cols[k];
        float s = inv[c];
        const float4 w = *(const float4*)(W + (size_t)c * EMB + d4 * 4);
        acc.x += w.x * s; acc.y += w.y * s; acc.z += w.z * s; acc.w += w.w * s;
    }
    acc.x += __shfl_xor(acc.x, 16); acc.y += __shfl_xor(acc.y, 16);
    acc.z += __shfl_xor(acc.z, 16); acc.w += __shfl_xor(acc.w, 16);
    acc.x += __shfl_xor(acc.x, 32); acc.y += __shfl_xor(acc.y, 32);
    acc.z += __shfl_xor(acc.z, 32); acc.w += __shfl_xor(acc.w, 32);
    if (sub == 0) {
        const float4 ws = *(const float4*)(W + (size_t)r * EMB + d4 * 4);
        const float4 bv = *(const float4*)(bb + d4 * 4);
        float4 o;
        o.x = fmaxf((acc.x + ws.x * inv_r) * inv_r + bv.x, 0.f);
        o.y = fmaxf((acc.y + ws.y * inv_r) * inv_r + bv.y, 0.f);
        o.z = fmaxf((acc.z + ws.z * inv_r) * inv_r + bv.z, 0.f);
        o.w = fmaxf((acc.w + ws.w * inv_r) * inv_r + bv.w, 0.f);
        *(float4*)(out + (size_t)r * EMB + d4 * 4) = o;
    }
}

extern "C" void kernel_launch(void* const* d_in, const int* in_sizes, int n_in,
                              void* d_out, int out_size, void* d_ws, size_t ws_size,
                              hipStream_t stream) {
    const int*   ue = (const int*)d_in[0];
    const int*   ie = (const int*)d_in[1];
    const float* Wu = (const float*)d_in[2];
    const float* bu = (const float*)d_in[3];
    const float* Wi = (const float*)d_in[4];
    const float* bi = (const float*)d_in[5];

    const int E_U = in_sizes[0] / 2;
    const int E_I = in_sizes[1] / 2;

    float* out_u = (float*)d_out;
    float* out_i = out_u + (size_t)NUSERS * EMB;

    // workspace layout (4-byte words); bcnt+claimed contiguous for one memset
    unsigned* w        = (unsigned*)d_ws;
    unsigned* bcnt_u   = w;            w += MAXB;     // zeroed
    unsigned* bcnt_i   = w;            w += MAXB;     // zeroed
    unsigned* claim_u  = w;            w += MAXB;     // zeroed
    unsigned* claim_i  = w;            w += MAXB;     // zeroed
    unsigned* boff_u   = w;            w += MAXB + 1;
    unsigned* boff_i   = w;            w += MAXB + 1;
    unsigned* part_u   = w;            w += MAXB;
    unsigned* part_i   = w;            w += MAXB;
    unsigned* deg_u    = w;            w += NUSERS;
    unsigned* deg_i    = w;            w += NITEMS;
    unsigned* offs_u   = w;            w += NUSERS + 1;
    unsigned* offs_i   = w;            w += NITEMS + 1;
    float*    inv_u    = (float*)w;    w += NUSERS;
    float*    inv_i    = (float*)w;    w += NITEMS;
    unsigned* pairs_u  = w;            w += E_U;
    unsigned* pairs_i  = w;            w += E_I;
    int*      cols_u   = (int*)w;      w += E_U;
    int*      cols_i   = (int*)w;      w += E_I;
    w += (size_t)(-(intptr_t)(w - (unsigned*)d_ws)) & 3;   // align to 16 B
    __half*   wh_u     = (__half*)w;   w += (size_t)NUSERS * EMB / 2;
    __half*   wh_i     = (__half*)w;   w += (size_t)NITEMS * EMB / 2;

    const size_t need_bytes = (size_t)((char*)w - (char*)d_ws);
    const bool use_half = (ws_size >= need_bytes);

    hipMemsetAsync(bcnt_u, 0, 4 * MAXB * sizeof(unsigned), stream);

    const int gb_u = (E_U + CHUNK - 1) / CHUNK;  // 293
    const int gb_i = (E_I + CHUNK - 1) / CHUNK;  // 147
    const int gg_u = (NUSERS + 3) / 4;           // 25000
    const int gg_i = (NITEMS + 3) / 4;           // 12500

    hist2_kernel     <<<gb_u + gb_i, 256, 0, stream>>>(ue, ie, bcnt_u, bcnt_i, E_U, E_I, gb_u);
    bscatter2_kernel <<<gb_u + gb_i, 256, 0, stream>>>(ue, ie, bcnt_u, bcnt_i, claim_u, claim_i,
                                                       boff_u, boff_i, pairs_u, pairs_i, E_U, E_I, gb_u);
    bdeginv2_kernel  <<<NB_U + NB_I, 256, 0, stream>>>(boff_u, boff_i, pairs_u, pairs_i,
                                                       deg_u, deg_i, inv_u, inv_i, part_u, part_i);
    scan3ffill_kernel<<<NB_U + NB_I, 256, 0, stream>>>(deg_u, deg_i, part_u, part_i, boff_u, boff_i,
                                                       pairs_u, pairs_i, offs_u, offs_i, cols_u, cols_i);
    if (use_half) {
        const int tot4 = (NUSERS + NITEMS) * EMB / 4;
        tohalf2_kernel <<<(tot4 + 255) / 256, 256, 0, stream>>>(Wu, Wi, inv_u, inv_i, wh_u, wh_i);
        gather2h_kernel<<<gg_u + gg_i, 256, 0, stream>>>(offs_u, offs_i, cols_u, cols_i,
                                                         wh_u, wh_i, bu, bi, inv_u, inv_i,
                                                         out_u, out_i, gg_u);
    } else {
        gather2f_kernel<<<gg_u + gg_i, 256, 0, stream>>>(offs_u, offs_i, cols_u, cols_i,
                                                         Wu, Wi, bu, bi, inv_u, inv_i,
                                                         out_u, out_i, gg_u);
    }
}

// Round 6
// 142.666 us; speedup vs baseline: 3.5926x; 1.0762x over previous
//
#include <hip/hip_runtime.h>
#include <hip/hip_fp16.h>

#define NUSERS 100000
#define NITEMS 50000
#define EMB 64
#define BROWS 1024      // rows per bucket
#define CHUNK 4096      // edges per block in bucket passes
#define MAXB 128        // max buckets (user: 98, item: 49)
#define CAP  16384      // padded bucket capacity (max real ~12.7K for uniform rows)
#define NB_U ((NUSERS + BROWS - 1) / BROWS)   // 98
#define NB_I ((NITEMS + BROWS - 1) / BROWS)   // 49

// packed pair: (local_row << 20) | col   (local_row < 1024, col < 2^17)

// ---- bucketed scatter with direct atomic slot allocation (no pre-histogram) ----
__global__ void bscatter2_kernel(const int* __restrict__ rowU, const int* __restrict__ rowI,
                                 unsigned* __restrict__ bcntU, unsigned* __restrict__ bcntI,
                                 unsigned* __restrict__ pairsU, unsigned* __restrict__ pairsI,
                                 int EU, int EI, int gbU) {
    __shared__ unsigned h[MAXB];
    __shared__ unsigned base[MAXB];
    const int* row; const int* col; unsigned* bcnt; unsigned* pairs; int E, blk, nb;
    if ((int)blockIdx.x < gbU) { row = rowU; col = rowU + EU; bcnt = bcntU; pairs = pairsU; E = EU; blk = blockIdx.x; nb = NB_U; }
    else                       { row = rowI; col = rowI + EI; bcnt = bcntI; pairs = pairsI; E = EI; blk = blockIdx.x - gbU; nb = NB_I; }
    int t = threadIdx.x;
    for (int i = t; i < nb; i += blockDim.x) h[i] = 0;
    __syncthreads();
    int lo = blk * CHUNK, hi = min(lo + CHUNK, E);
    for (int i = lo + t; i < hi; i += blockDim.x)
        atomicAdd(&h[row[i] >> 10], 1u);
    __syncthreads();
    for (int i = t; i < nb; i += blockDim.x) {
        unsigned cnt = h[i];
        base[i] = cnt ? ((unsigned)i * CAP + atomicAdd(&bcnt[i], cnt)) : 0u;
        h[i] = 0;
    }
    __syncthreads();
    for (int i = lo + t; i < hi; i += blockDim.x) {
        int r = row[i];
        int b = r >> 10;
        unsigned p = base[b] + atomicAdd(&h[b], 1u);
        pairs[p] = ((unsigned)(r & 1023) << 20) | (unsigned)col[i];
    }
}

// ---- per-bucket degree + inv + bucket degree-sum (part) ----
__global__ void bdeginv2_kernel(const unsigned* __restrict__ bcntU, const unsigned* __restrict__ bcntI,
                                const unsigned* __restrict__ pairsU, const unsigned* __restrict__ pairsI,
                                unsigned* __restrict__ degU, unsigned* __restrict__ degI,
                                float* __restrict__ invU, float* __restrict__ invI,
                                unsigned* __restrict__ partU, unsigned* __restrict__ partI) {
    __shared__ unsigned d[BROWS];
    __shared__ unsigned red[256];
    const unsigned* bcnt; const unsigned* pairs; unsigned* deg; float* inv; unsigned* part; int n, b;
    if ((int)blockIdx.x < NB_U) { bcnt = bcntU; pairs = pairsU; deg = degU; inv = invU; part = partU; n = NUSERS; b = blockIdx.x; }
    else                        { bcnt = bcntI; pairs = pairsI; deg = degI; inv = invI; part = partI; n = NITEMS; b = blockIdx.x - NB_U; }
    int rbase = b * BROWS;
    int nrows = min(BROWS, n - rbase);
    for (int i = threadIdx.x; i < nrows; i += blockDim.x) d[i] = 0;
    __syncthreads();
    unsigned lo = (unsigned)b * CAP, hi = lo + bcnt[b];
    for (unsigned i = lo + threadIdx.x; i < hi; i += blockDim.x)
        atomicAdd(&d[pairs[i] >> 20], 1u);
    __syncthreads();
    unsigned s = 0;
    for (int i = threadIdx.x; i < nrows; i += blockDim.x) {
        unsigned v = d[i];
        deg[rbase + i] = v;
        inv[rbase + i] = rsqrtf((float)(v + 1u));
        s += v;
    }
    red[threadIdx.x] = s;
    __syncthreads();
    for (int off = 128; off > 0; off >>= 1) {
        if ((int)threadIdx.x < off) red[threadIdx.x] += red[threadIdx.x + off];
        __syncthreads();
    }
    if (threadIdx.x == 0) part[b] = red[0];
}

// ---- part-scan + per-bucket deg scan -> offs, + fine fill, one pass ----
__global__ void scan3ffill_kernel(const unsigned* __restrict__ degU, const unsigned* __restrict__ degI,
                                  const unsigned* __restrict__ partU, const unsigned* __restrict__ partI,
                                  const unsigned* __restrict__ bcntU, const unsigned* __restrict__ bcntI,
                                  const unsigned* __restrict__ pairsU, const unsigned* __restrict__ pairsI,
                                  unsigned* __restrict__ offsU, unsigned* __restrict__ offsI,
                                  int* __restrict__ colsU, int* __restrict__ colsI) {
    __shared__ unsigned sh[256];
    __shared__ unsigned c[BROWS];
    __shared__ unsigned pt[MAXB + 1];
    const unsigned* deg; const unsigned* part; const unsigned* bcnt; const unsigned* pairs;
    unsigned* offs; int* cols; int n, b, nb;
    if ((int)blockIdx.x < NB_U) { deg = degU; part = partU; bcnt = bcntU; pairs = pairsU; offs = offsU; cols = colsU; n = NUSERS; b = blockIdx.x; nb = NB_U; }
    else                        { deg = degI; part = partI; bcnt = bcntI; pairs = pairsI; offs = offsI; cols = colsI; n = NITEMS; b = blockIdx.x - NB_U; nb = NB_I; }
    int t = threadIdx.x;
    if (t < nb) pt[t] = part[t];
    __syncthreads();
    if (t == 0) {                       // exclusive scan of bucket sums in LDS
        unsigned run = 0;
        for (int i = 0; i < nb; i++) { unsigned x = pt[i]; pt[i] = run; run += x; }
        pt[nb] = run;
    }
    __syncthreads();
    unsigned pbase = pt[b];
    if (b == nb - 1 && t == 0) offs[n] = pt[nb];
    // block scan of this bucket's degrees
    int rbase = b * BROWS;
    int base = rbase + t * 4;
    unsigned v[4], s = 0;
    for (int i = 0; i < 4; i++) {
        int idx = base + i;
        v[i] = (idx < n) ? deg[idx] : 0u;
        s += v[i];
    }
    sh[t] = s;
    __syncthreads();
    for (int off = 1; off < 256; off <<= 1) {
        unsigned add = (t >= off) ? sh[t - off] : 0u;
        __syncthreads();
        sh[t] += add;
        __syncthreads();
    }
    unsigned running = pbase + sh[t] - s;
    for (int i = 0; i < 4; i++) {
        int idx = base + i;
        if (idx < n) { offs[idx] = running; c[t * 4 + i] = running; running += v[i]; }
    }
    __syncthreads();
    // fine fill from padded pairs via LDS cursors
    unsigned lo = (unsigned)b * CAP, hi = lo + bcnt[b];
    for (unsigned i = lo + t; i < hi; i += blockDim.x) {
        unsigned pk = pairs[i];
        unsigned p = atomicAdd(&c[pk >> 20], 1u);
        cols[p] = (int)(pk & 0xFFFFFu);
    }
}

// ---- W*inv[row] -> f16 copies (pre-scaled by source-node norm) ----
// NOTE: Wh overlays the (now dead) pairs region; runs after scan3ffill.
__global__ void tohalf2_kernel(const float* __restrict__ WU, const float* __restrict__ WI,
                               const float* __restrict__ invU, const float* __restrict__ invI,
                               __half* __restrict__ WhU, __half* __restrict__ WhI) {
    const int totU = NUSERS * EMB / 4;
    const int totI = NITEMS * EMB / 4;
    int i = blockIdx.x * 256 + threadIdx.x;
    const float* W; const float* inv; __half* Wh;
    if (i < totU)             { W = WU; inv = invU; Wh = WhU; }
    else if (i < totU + totI) { i -= totU; W = WI; inv = invI; Wh = WhI; }
    else return;
    int r = i >> 4;                 // 16 float4s per row
    float s = inv[r];
    float4 w = ((const float4*)W)[i];
    __half2 h0 = __floats2half2_rn(w.x * s, w.y * s);
    __half2 h1 = __floats2half2_rn(w.z * s, w.w * s);
    ((__half2*)Wh)[2 * i]     = h0;
    ((__half2*)Wh)[2 * i + 1] = h1;
}

// ---- gather, f16, register-hoisted cols: one wave per row ----
// lanes: sub = lane>>3 (8 edges in flight), d8 = lane&7 (16B slice of the 128B row)
__global__ void gather2h_kernel(const unsigned* __restrict__ offsU, const unsigned* __restrict__ offsI,
                                const int* __restrict__ colsU, const int* __restrict__ colsI,
                                const __half* __restrict__ WhU, const __half* __restrict__ WhI,
                                const float* __restrict__ bU, const float* __restrict__ bI,
                                const float* __restrict__ invU, const float* __restrict__ invI,
                                float* __restrict__ outU, float* __restrict__ outI, int gbU) {
    const unsigned* offs; const int* cols; const __half* Wh; const float* bb; const float* inv;
    float* out; int n, r0;
    if ((int)blockIdx.x < gbU) { offs = offsU; cols = colsU; Wh = WhU; bb = bU; inv = invU; out = outU; n = NUSERS; r0 = blockIdx.x * 4; }
    else                       { offs = offsI; cols = colsI; Wh = WhI; bb = bI; inv = invI; out = outI; n = NITEMS; r0 = (blockIdx.x - gbU) * 4; }
    int r = r0 + (threadIdx.x >> 6);
    if (r >= n) return;
    int lane = threadIdx.x & 63;
    int sub = lane >> 3;
    int d8  = lane & 7;
    unsigned beg = offs[r], end = offs[r + 1];
    float2 acc[4] = {{0.f,0.f},{0.f,0.f},{0.f,0.f},{0.f,0.f}};
    for (unsigned gb = beg; gb < end; gb += 64) {
        int nfl = (int)min(64u, end - gb);
        int cl = (lane < nfl) ? cols[gb + lane] : 0;   // coalesced, once per 64 edges
        int ngrp = (nfl + 7) >> 3;
        for (int g = 0; g < ngrp; ++g) {
            int idx = g * 8 + sub;
            int c = __shfl(cl, idx);                   // VALU/LDS-pipe only, no mem dep
            if (idx < nfl) {
                union { float4 f; __half2 h[4]; } u;
                u.f = *(const float4*)(Wh + (size_t)c * EMB + d8 * 8);
                #pragma unroll
                for (int j = 0; j < 4; j++) {
                    float2 tv = __half22float2(u.h[j]);
                    acc[j].x += tv.x; acc[j].y += tv.y;
                }
            }
        }
    }
    #pragma unroll
    for (int m = 8; m < 64; m <<= 1) {
        #pragma unroll
        for (int j = 0; j < 4; j++) {
            acc[j].x += __shfl_xor(acc[j].x, m);
            acc[j].y += __shfl_xor(acc[j].y, m);
        }
    }
    if (sub == 0) {
        float inv_r = inv[r];
        union { float4 f; __half2 h[4]; } us;
        us.f = *(const float4*)(Wh + (size_t)r * EMB + d8 * 8);   // self loop: Wh[r]*inv_r = W[r]*inv_r^2
        const float4 bv0 = *(const float4*)(bb + d8 * 8);
        const float4 bv1 = *(const float4*)(bb + d8 * 8 + 4);
        float2 s0 = __half22float2(us.h[0]);
        float2 s1 = __half22float2(us.h[1]);
        float2 s2 = __half22float2(us.h[2]);
        float2 s3 = __half22float2(us.h[3]);
        float4 o0, o1;
        o0.x = fmaxf((acc[0].x + s0.x) * inv_r + bv0.x, 0.f);
        o0.y = fmaxf((acc[0].y + s0.y) * inv_r + bv0.y, 0.f);
        o0.z = fmaxf((acc[1].x + s1.x) * inv_r + bv0.z, 0.f);
        o0.w = fmaxf((acc[1].y + s1.y) * inv_r + bv0.w, 0.f);
        o1.x = fmaxf((acc[2].x + s2.x) * inv_r + bv1.x, 0.f);
        o1.y = fmaxf((acc[2].y + s2.y) * inv_r + bv1.y, 0.f);
        o1.z = fmaxf((acc[3].x + s3.x) * inv_r + bv1.z, 0.f);
        o1.w = fmaxf((acc[3].y + s3.y) * inv_r + bv1.w, 0.f);
        *(float4*)(out + (size_t)r * EMB + d8 * 8)     = o0;
        *(float4*)(out + (size_t)r * EMB + d8 * 8 + 4) = o1;
    }
}

// ---- f32 fallback gather (if workspace too small for f16 copies) ----
__global__ void gather2f_kernel(const unsigned* __restrict__ offsU, const unsigned* __restrict__ offsI,
                                const int* __restrict__ colsU, const int* __restrict__ colsI,
                                const float* __restrict__ WU, const float* __restrict__ WI,
                                const float* __restrict__ bU, const float* __restrict__ bI,
                                const float* __restrict__ invU, const float* __restrict__ invI,
                                float* __restrict__ outU, float* __restrict__ outI, int gbU) {
    const unsigned* offs; const int* cols; const float* W; const float* bb; const float* inv;
    float* out; int n, r0;
    if ((int)blockIdx.x < gbU) { offs = offsU; cols = colsU; W = WU; bb = bU; inv = invU; out = outU; n = NUSERS; r0 = blockIdx.x * 4; }
    else                       { offs = offsI; cols = colsI; W = WI; bb = bI; inv = invI; out = outI; n = NITEMS; r0 = (blockIdx.x - gbU) * 4; }
    int r = r0 + (threadIdx.x >> 6);
    if (r >= n) return;
    int lane = threadIdx.x & 63;
    int sub = lane >> 4;
    int d4 = lane & 15;
    unsigned beg = offs[r], end = offs[r + 1];
    float inv_r = inv[r];
    float4 acc = make_float4(0.f, 0.f, 0.f, 0.f);
    for (unsigned k = beg + sub; k < end; k += 4) {
        int c = cols[k];
        float s = inv[c];
        const float4 w = *(const float4*)(W + (size_t)c * EMB + d4 * 4);
        acc.x += w.x * s; acc.y += w.y * s; acc.z += w.z * s; acc.w += w.w * s;
    }
    acc.x += __shfl_xor(acc.x, 16); acc.y += __shfl_xor(acc.y, 16);
    acc.z += __shfl_xor(acc.z, 16); acc.w += __shfl_xor(acc.w, 16);
    acc.x += __shfl_xor(acc.x, 32); acc.y += __shfl_xor(acc.y, 32);
    acc.z += __shfl_xor(acc.z, 32); acc.w += __shfl_xor(acc.w, 32);
    if (sub == 0) {
        const float4 ws = *(const float4*)(W + (size_t)r * EMB + d4 * 4);
        const float4 bv = *(const float4*)(bb + d4 * 4);
        float4 o;
        o.x = fmaxf((acc.x + ws.x * inv_r) * inv_r + bv.x, 0.f);
        o.y = fmaxf((acc.y + ws.y * inv_r) * inv_r + bv.y, 0.f);
        o.z = fmaxf((acc.z + ws.z * inv_r) * inv_r + bv.z, 0.f);
        o.w = fmaxf((acc.w + ws.w * inv_r) * inv_r + bv.w, 0.f);
        *(float4*)(out + (size_t)r * EMB + d4 * 4) = o;
    }
}

extern "C" void kernel_launch(void* const* d_in, const int* in_sizes, int n_in,
                              void* d_out, int out_size, void* d_ws, size_t ws_size,
                              hipStream_t stream) {
    const int*   ue = (const int*)d_in[0];
    const int*   ie = (const int*)d_in[1];
    const float* Wu = (const float*)d_in[2];
    const float* bu = (const float*)d_in[3];
    const float* Wi = (const float*)d_in[4];
    const float* bi = (const float*)d_in[5];

    const int E_U = in_sizes[0] / 2;
    const int E_I = in_sizes[1] / 2;

    float* out_u = (float*)d_out;
    float* out_i = out_u + (size_t)NUSERS * EMB;

    // workspace layout (4-byte words); Wh overlays the dead pairs region
    unsigned* w       = (unsigned*)d_ws;
    unsigned* bcnt_u  = w;            w += MAXB;     // zeroed
    unsigned* bcnt_i  = w;            w += MAXB;     // zeroed
    unsigned* part_u  = w;            w += MAXB;
    unsigned* part_i  = w;            w += MAXB;
    unsigned* deg_u   = w;            w += NUSERS;
    unsigned* deg_i   = w;            w += NITEMS;
    unsigned* offs_u  = w;            w += NUSERS + 1;
    unsigned* offs_i  = w;            w += NITEMS + 1;
    float*    inv_u   = (float*)w;    w += NUSERS;
    float*    inv_i   = (float*)w;    w += NITEMS;
    int*      cols_u  = (int*)w;      w += E_U;
    int*      cols_i  = (int*)w;      w += E_I;
    w += (size_t)(-(intptr_t)(w - (unsigned*)d_ws)) & 3;   // align to 16 B
    // union region: pairs (build phase) / Wh (gather phase)
    unsigned* un      = w;
    unsigned* pairs_u = un;                            // NB_U*CAP words
    unsigned* pairs_i = un + (size_t)NB_U * CAP;       // NB_I*CAP words
    __half*   wh_u    = (__half*)un;                   // NUSERS*EMB halfs
    __half*   wh_i    = (__half*)un + (size_t)NUSERS * EMB;
    size_t un_words_pairs = (size_t)(NB_U + NB_I) * CAP;
    size_t un_words_wh    = (size_t)(NUSERS + NITEMS) * EMB / 2;
    size_t un_words = un_words_pairs > un_words_wh ? un_words_pairs : un_words_wh;
    const size_t need_bytes = (size_t)((char*)(un + un_words) - (char*)d_ws);
    const bool use_half = (ws_size >= need_bytes);

    hipMemsetAsync(bcnt_u, 0, 2 * MAXB * sizeof(unsigned), stream);

    const int gb_u = (E_U + CHUNK - 1) / CHUNK;  // 293
    const int gb_i = (E_I + CHUNK - 1) / CHUNK;  // 147
    const int gg_u = (NUSERS + 3) / 4;           // 25000
    const int gg_i = (NITEMS + 3) / 4;           // 12500

    bscatter2_kernel <<<gb_u + gb_i, 256, 0, stream>>>(ue, ie, bcnt_u, bcnt_i,
                                                       pairs_u, pairs_i, E_U, E_I, gb_u);
    bdeginv2_kernel  <<<NB_U + NB_I, 256, 0, stream>>>(bcnt_u, bcnt_i, pairs_u, pairs_i,
                                                       deg_u, deg_i, inv_u, inv_i, part_u, part_i);
    scan3ffill_kernel<<<NB_U + NB_I, 256, 0, stream>>>(deg_u, deg_i, part_u, part_i, bcnt_u, bcnt_i,
                                                       pairs_u, pairs_i, offs_u, offs_i, cols_u, cols_i);
    if (use_half) {
        const int tot4 = (NUSERS + NITEMS) * EMB / 4;
        tohalf2_kernel <<<(tot4 + 255) / 256, 256, 0, stream>>>(Wu, Wi, inv_u, inv_i, wh_u, wh_i);
        gather2h_kernel<<<gg_u + gg_i, 256, 0, stream>>>(offs_u, offs_i, cols_u, cols_i,
                                                         wh_u, wh_i, bu, bi, inv_u, inv_i,
                                                         out_u, out_i, gg_u);
    } else {
        gather2f_kernel<<<gg_u + gg_i, 256, 0, stream>>>(offs_u, offs_i, cols_u, cols_i,
                                                         Wu, Wi, bu, bi, inv_u, inv_i,
                                                         out_u, out_i, gg_u);
    }
}

// Round 7
// 136.649 us; speedup vs baseline: 3.7508x; 1.0440x over previous
//
#include <hip/hip_runtime.h>
#include <hip/hip_fp16.h>

#define NUSERS 100000
#define NITEMS 50000
#define EMB 64
#define BROWS 1024      // rows per bucket
#define CHUNK 4096      // edges per block in bucket passes
#define MAXB 128        // max buckets (user: 98, item: 49)
#define CAP  16384      // padded bucket capacity (expected ~12.3K, 37 sigma headroom)
#define NB_U ((NUSERS + BROWS - 1) / BROWS)   // 98
#define NB_I ((NITEMS + BROWS - 1) / BROWS)   // 49

// packed pair: (local_row << 20) | col   (local_row < 1024, col < 2^17)

// ---- bucketed scatter with direct atomic slot allocation ----
__global__ void bscatter2_kernel(const int* __restrict__ rowU, const int* __restrict__ rowI,
                                 unsigned* __restrict__ bcntU, unsigned* __restrict__ bcntI,
                                 unsigned* __restrict__ pairsU, unsigned* __restrict__ pairsI,
                                 int EU, int EI, int gbU) {
    __shared__ unsigned h[MAXB];
    __shared__ unsigned base[MAXB];
    const int* row; const int* col; unsigned* bcnt; unsigned* pairs; int E, blk, nb;
    if ((int)blockIdx.x < gbU) { row = rowU; col = rowU + EU; bcnt = bcntU; pairs = pairsU; E = EU; blk = blockIdx.x; nb = NB_U; }
    else                       { row = rowI; col = rowI + EI; bcnt = bcntI; pairs = pairsI; E = EI; blk = blockIdx.x - gbU; nb = NB_I; }
    int t = threadIdx.x;
    for (int i = t; i < nb; i += blockDim.x) h[i] = 0;
    __syncthreads();
    int lo = blk * CHUNK, hi = min(lo + CHUNK, E);
    for (int i = lo + t; i < hi; i += blockDim.x)
        atomicAdd(&h[row[i] >> 10], 1u);
    __syncthreads();
    for (int i = t; i < nb; i += blockDim.x) {
        unsigned cnt = h[i];
        base[i] = cnt ? ((unsigned)i * CAP + atomicAdd(&bcnt[i], cnt)) : 0u;
        h[i] = 0;
    }
    __syncthreads();
    for (int i = lo + t; i < hi; i += blockDim.x) {
        int r = row[i];
        int b = r >> 10;
        unsigned p = base[b] + atomicAdd(&h[b], 1u);
        pairs[p] = ((unsigned)(r & 1023) << 20) | (unsigned)col[i];
    }
}

// ---- fused per-bucket: degree count + inv + block scan + atomic base alloc + fine fill ----
// Row offsets are allocated per bucket via one global atomic, so no global scan pass
// is needed; gather reads (off,deg) as a uint2 instead of offs[r]/offs[r+1].
__global__ void bprep_kernel(const unsigned* __restrict__ bcntU, const unsigned* __restrict__ bcntI,
                             const unsigned* __restrict__ pairsU, const unsigned* __restrict__ pairsI,
                             uint2* __restrict__ odU, uint2* __restrict__ odI,
                             float* __restrict__ invU, float* __restrict__ invI,
                             int* __restrict__ colsU, int* __restrict__ colsI,
                             unsigned* __restrict__ totU, unsigned* __restrict__ totI) {
    __shared__ unsigned d[BROWS];
    __shared__ unsigned c[BROWS];
    __shared__ unsigned sh[256];
    __shared__ unsigned sbase;
    const unsigned* bcnt; const unsigned* pairs; uint2* od; float* inv; int* cols; unsigned* tot; int n, b;
    if ((int)blockIdx.x < NB_U) { bcnt = bcntU; pairs = pairsU; od = odU; inv = invU; cols = colsU; tot = totU; n = NUSERS; b = blockIdx.x; }
    else                        { bcnt = bcntI; pairs = pairsI; od = odI; inv = invI; cols = colsI; tot = totI; n = NITEMS; b = blockIdx.x - NB_U; }
    int t = threadIdx.x;
    int rbase = b * BROWS;
    for (int i = t; i < BROWS; i += 256) d[i] = 0;
    __syncthreads();
    unsigned lo = (unsigned)b * CAP, hi = lo + bcnt[b];
    for (unsigned i = lo + t; i < hi; i += 256)
        atomicAdd(&d[pairs[i] >> 20], 1u);
    __syncthreads();
    unsigned v[4], s = 0;
    #pragma unroll
    for (int i = 0; i < 4; i++) { v[i] = d[t * 4 + i]; s += v[i]; }
    sh[t] = s;
    __syncthreads();
    for (int off = 1; off < 256; off <<= 1) {
        unsigned add = (t >= off) ? sh[t - off] : 0u;
        __syncthreads();
        sh[t] += add;
        __syncthreads();
    }
    if (t == 255) sbase = atomicAdd(tot, sh[255]);   // bucket's base in cols[]
    __syncthreads();
    unsigned running = sbase + sh[t] - s;
    #pragma unroll
    for (int i = 0; i < 4; i++) {
        int li = t * 4 + i;
        int idx = rbase + li;
        if (idx < n) {
            od[idx] = make_uint2(running, v[i]);
            inv[idx] = rsqrtf((float)(v[i] + 1u));
            c[li] = running;
            running += v[i];
        }
    }
    __syncthreads();
    for (unsigned i = lo + t; i < hi; i += 256) {
        unsigned pk = pairs[i];
        unsigned p = atomicAdd(&c[pk >> 20], 1u);
        cols[p] = (int)(pk & 0xFFFFFu);
    }
}

// ---- W*inv[row] -> f16 copies (pre-scaled by source-node norm); overlays dead pairs ----
__global__ void tohalf2_kernel(const float* __restrict__ WU, const float* __restrict__ WI,
                               const float* __restrict__ invU, const float* __restrict__ invI,
                               __half* __restrict__ WhU, __half* __restrict__ WhI) {
    const int totU = NUSERS * EMB / 4;
    const int totI = NITEMS * EMB / 4;
    int i = blockIdx.x * 256 + threadIdx.x;
    const float* W; const float* inv; __half* Wh;
    if (i < totU)             { W = WU; inv = invU; Wh = WhU; }
    else if (i < totU + totI) { i -= totU; W = WI; inv = invI; Wh = WhI; }
    else return;
    int r = i >> 4;                 // 16 float4s per row
    float s = inv[r];
    float4 w = ((const float4*)W)[i];
    __half2 h0 = __floats2half2_rn(w.x * s, w.y * s);
    __half2 h1 = __floats2half2_rn(w.z * s, w.w * s);
    ((__half2*)Wh)[2 * i]     = h0;
    ((__half2*)Wh)[2 * i + 1] = h1;
}

__device__ __forceinline__ void acc8(float* acc, float4 f) {
    const __half2* h = (const __half2*)&f;
    #pragma unroll
    for (int j = 0; j < 4; j++) {
        float2 tv = __half22float2(h[j]);
        acc[2 * j]     += tv.x;
        acc[2 * j + 1] += tv.y;
    }
}

// ---- gather, f16: 8 lanes per row (d8 = 16B slice), 8 rows per wave, serial edge
// loop with 2-way unroll. No cross-lane reduction, no shfl broadcast. ----
__global__ void gather2h_kernel(const uint2* __restrict__ odU, const uint2* __restrict__ odI,
                                const int* __restrict__ colsU, const int* __restrict__ colsI,
                                const __half* __restrict__ WhU, const __half* __restrict__ WhI,
                                const float* __restrict__ bU, const float* __restrict__ bI,
                                const float* __restrict__ invU, const float* __restrict__ invI,
                                float* __restrict__ outU, float* __restrict__ outI, int ggU) {
    const uint2* od; const int* cols; const __half* Wh; const float* bb; const float* inv;
    float* out; int n, r0;
    if ((int)blockIdx.x < ggU) { od = odU; cols = colsU; Wh = WhU; bb = bU; inv = invU; out = outU; n = NUSERS; r0 = blockIdx.x * 32; }
    else                       { od = odI; cols = colsI; Wh = WhI; bb = bI; inv = invI; out = outI; n = NITEMS; r0 = (blockIdx.x - ggU) * 32; }
    int r = r0 + (threadIdx.x >> 3);
    if (r >= n) return;
    int d8 = threadIdx.x & 7;
    uint2 o = od[r];
    unsigned k = o.x, end = o.x + o.y;
    const __half* wb = Wh + d8 * 8;
    float acc[8] = {0.f, 0.f, 0.f, 0.f, 0.f, 0.f, 0.f, 0.f};
    for (; k + 2 <= end; k += 2) {
        int c0 = cols[k];
        int c1 = cols[k + 1];
        float4 f0 = *(const float4*)(wb + (size_t)c0 * EMB);
        float4 f1 = *(const float4*)(wb + (size_t)c1 * EMB);
        acc8(acc, f0);
        acc8(acc, f1);
    }
    if (k < end) {
        int c0 = cols[k];
        float4 f0 = *(const float4*)(wb + (size_t)c0 * EMB);
        acc8(acc, f0);
    }
    // epilogue: out = relu((acc + Wh[r]) * inv_r + b)   (Wh[r]*inv_r = W[r]*inv_r^2)
    float inv_r = inv[r];
    float4 fs = *(const float4*)(Wh + (size_t)r * EMB + d8 * 8);
    float sf[8];
    {
        const __half2* h = (const __half2*)&fs;
        #pragma unroll
        for (int j = 0; j < 4; j++) {
            float2 tv = __half22float2(h[j]);
            sf[2 * j] = tv.x; sf[2 * j + 1] = tv.y;
        }
    }
    const float4 bv0 = *(const float4*)(bb + d8 * 8);
    const float4 bv1 = *(const float4*)(bb + d8 * 8 + 4);
    float4 o0, o1;
    o0.x = fmaxf((acc[0] + sf[0]) * inv_r + bv0.x, 0.f);
    o0.y = fmaxf((acc[1] + sf[1]) * inv_r + bv0.y, 0.f);
    o0.z = fmaxf((acc[2] + sf[2]) * inv_r + bv0.z, 0.f);
    o0.w = fmaxf((acc[3] + sf[3]) * inv_r + bv0.w, 0.f);
    o1.x = fmaxf((acc[4] + sf[4]) * inv_r + bv1.x, 0.f);
    o1.y = fmaxf((acc[5] + sf[5]) * inv_r + bv1.y, 0.f);
    o1.z = fmaxf((acc[6] + sf[6]) * inv_r + bv1.z, 0.f);
    o1.w = fmaxf((acc[7] + sf[7]) * inv_r + bv1.w, 0.f);
    *(float4*)(out + (size_t)r * EMB + d8 * 8)     = o0;
    *(float4*)(out + (size_t)r * EMB + d8 * 8 + 4) = o1;
}

// ---- f32 fallback gather (if workspace too small for f16 copies) ----
__global__ void gather2f_kernel(const uint2* __restrict__ odU, const uint2* __restrict__ odI,
                                const int* __restrict__ colsU, const int* __restrict__ colsI,
                                const float* __restrict__ WU, const float* __restrict__ WI,
                                const float* __restrict__ bU, const float* __restrict__ bI,
                                const float* __restrict__ invU, const float* __restrict__ invI,
                                float* __restrict__ outU, float* __restrict__ outI, int ggU) {
    const uint2* od; const int* cols; const float* W; const float* bb; const float* inv;
    float* out; int n, r0;
    if ((int)blockIdx.x < ggU) { od = odU; cols = colsU; W = WU; bb = bU; inv = invU; out = outU; n = NUSERS; r0 = blockIdx.x * 32; }
    else                       { od = odI; cols = colsI; W = WI; bb = bI; inv = invI; out = outI; n = NITEMS; r0 = (blockIdx.x - ggU) * 32; }
    int r = r0 + (threadIdx.x >> 3);
    if (r >= n) return;
    int d8 = threadIdx.x & 7;
    uint2 o = od[r];
    unsigned k = o.x, end = o.x + o.y;
    const float* wb = W + d8 * 8;
    float acc[8] = {0.f, 0.f, 0.f, 0.f, 0.f, 0.f, 0.f, 0.f};
    for (; k < end; ++k) {
        int c0 = cols[k];
        float ic = inv[c0];
        float4 f0 = *(const float4*)(wb + (size_t)c0 * EMB);
        float4 f1 = *(const float4*)(wb + (size_t)c0 * EMB + 4);
        acc[0] += f0.x * ic; acc[1] += f0.y * ic; acc[2] += f0.z * ic; acc[3] += f0.w * ic;
        acc[4] += f1.x * ic; acc[5] += f1.y * ic; acc[6] += f1.z * ic; acc[7] += f1.w * ic;
    }
    float inv_r = inv[r];
    float4 s0 = *(const float4*)(W + (size_t)r * EMB + d8 * 8);
    float4 s1 = *(const float4*)(W + (size_t)r * EMB + d8 * 8 + 4);
    const float4 bv0 = *(const float4*)(bb + d8 * 8);
    const float4 bv1 = *(const float4*)(bb + d8 * 8 + 4);
    float4 o0, o1;
    o0.x = fmaxf((acc[0] + s0.x * inv_r) * inv_r + bv0.x, 0.f);
    o0.y = fmaxf((acc[1] + s0.y * inv_r) * inv_r + bv0.y, 0.f);
    o0.z = fmaxf((acc[2] + s0.z * inv_r) * inv_r + bv0.z, 0.f);
    o0.w = fmaxf((acc[3] + s0.w * inv_r) * inv_r + bv0.w, 0.f);
    o1.x = fmaxf((acc[4] + s1.x * inv_r) * inv_r + bv1.x, 0.f);
    o1.y = fmaxf((acc[5] + s1.y * inv_r) * inv_r + bv1.y, 0.f);
    o1.z = fmaxf((acc[6] + s1.z * inv_r) * inv_r + bv1.z, 0.f);
    o1.w = fmaxf((acc[7] + s1.w * inv_r) * inv_r + bv1.w, 0.f);
    *(float4*)(out + (size_t)r * EMB + d8 * 8)     = o0;
    *(float4*)(out + (size_t)r * EMB + d8 * 8 + 4) = o1;
}

extern "C" void kernel_launch(void* const* d_in, const int* in_sizes, int n_in,
                              void* d_out, int out_size, void* d_ws, size_t ws_size,
                              hipStream_t stream) {
    const int*   ue = (const int*)d_in[0];
    const int*   ie = (const int*)d_in[1];
    const float* Wu = (const float*)d_in[2];
    const float* bu = (const float*)d_in[3];
    const float* Wi = (const float*)d_in[4];
    const float* bi = (const float*)d_in[5];

    const int E_U = in_sizes[0] / 2;
    const int E_I = in_sizes[1] / 2;

    float* out_u = (float*)d_out;
    float* out_i = out_u + (size_t)NUSERS * EMB;

    // workspace layout (4-byte words); Wh overlays the dead pairs region
    unsigned* w       = (unsigned*)d_ws;
    unsigned* bcnt_u  = w;            w += MAXB;     // zeroed
    unsigned* bcnt_i  = w;            w += MAXB;     // zeroed
    unsigned* tot_u   = w;            w += 1;        // zeroed
    unsigned* tot_i   = w;            w += 1;        // zeroed
    uint2*    od_u    = (uint2*)w;    w += 2 * (size_t)NUSERS;
    uint2*    od_i    = (uint2*)w;    w += 2 * (size_t)NITEMS;
    float*    inv_u   = (float*)w;    w += NUSERS;
    float*    inv_i   = (float*)w;    w += NITEMS;
    int*      cols_u  = (int*)w;      w += E_U;
    int*      cols_i  = (int*)w;      w += E_I;
    w += (size_t)(-(intptr_t)(w - (unsigned*)d_ws)) & 3;   // align to 16 B
    // union region: pairs (build phase) / Wh (gather phase)
    unsigned* un      = w;
    unsigned* pairs_u = un;                            // NB_U*CAP words
    unsigned* pairs_i = un + (size_t)NB_U * CAP;       // NB_I*CAP words
    __half*   wh_u    = (__half*)un;                   // NUSERS*EMB halfs
    __half*   wh_i    = (__half*)un + (size_t)NUSERS * EMB;
    size_t un_words_pairs = (size_t)(NB_U + NB_I) * CAP;
    size_t un_words_wh    = (size_t)(NUSERS + NITEMS) * EMB / 2;
    size_t un_words = un_words_pairs > un_words_wh ? un_words_pairs : un_words_wh;
    const size_t need_bytes = (size_t)((char*)(un + un_words) - (char*)d_ws);
    const bool use_half = (ws_size >= need_bytes);

    hipMemsetAsync(bcnt_u, 0, (2 * MAXB + 2) * sizeof(unsigned), stream);

    const int gb_u = (E_U + CHUNK - 1) / CHUNK;  // 293
    const int gb_i = (E_I + CHUNK - 1) / CHUNK;  // 147
    const int gg_u = (NUSERS + 31) / 32;         // 3125
    const int gg_i = (NITEMS + 31) / 32;         // 1563

    bscatter2_kernel<<<gb_u + gb_i, 256, 0, stream>>>(ue, ie, bcnt_u, bcnt_i,
                                                      pairs_u, pairs_i, E_U, E_I, gb_u);
    bprep_kernel    <<<NB_U + NB_I, 256, 0, stream>>>(bcnt_u, bcnt_i, pairs_u, pairs_i,
                                                      od_u, od_i, inv_u, inv_i,
                                                      cols_u, cols_i, tot_u, tot_i);
    if (use_half) {
        const int tot4 = (NUSERS + NITEMS) * EMB / 4;
        tohalf2_kernel <<<(tot4 + 255) / 256, 256, 0, stream>>>(Wu, Wi, inv_u, inv_i, wh_u, wh_i);
        gather2h_kernel<<<gg_u + gg_i, 256, 0, stream>>>(od_u, od_i, cols_u, cols_i,
                                                         wh_u, wh_i, bu, bi, inv_u, inv_i,
                                                         out_u, out_i, gg_u);
    } else {
        gather2f_kernel<<<gg_u + gg_i, 256, 0, stream>>>(od_u, od_i, cols_u, cols_i,
                                                         Wu, Wi, bu, bi, inv_u, inv_i,
                                                         out_u, out_i, gg_u);
    }
}